// Round 1
// baseline (213.912 us; speedup 1.0000x reference)
//
#include <hip/hip_runtime.h>
#include <hip/hip_bf16.h>
#include <math.h>

// Differential attention, bf16 MFMA pipeline.
// ws layout (bytes):
//   [0,4M)    xb      x as bf16             2048x1024
//   [4M,10M)  w1      [Wq;Wk;Wv] bf16       3072x1024
//   [10M,12M) wob     Wo bf16               1024x1024
//   [12M,24M) qkv     bf16, row stride 3072 (q|k|v); rope applied in-place to q,k
//   [24M,28M) vt      v transposed bf16     1024x2048  vt[d][s]
//   [28M,32M) atn     normalized wv bf16    2048x1024
//   [32M,+256K) cos/sin tables fp32         2048x16 each

typedef __bf16 bf16x8 __attribute__((ext_vector_type(8)));
typedef float f32x4 __attribute__((ext_vector_type(4)));

#define LOG2E 1.4426950408889634f
#define SCALE 0.17677669529663687f /* 1/sqrt(32) */
#define LAM_INIT 0.783605766532f
#define ONE_M_LI 0.216394233468f

__device__ __forceinline__ ushort f2b(float f) {
  unsigned u = __builtin_bit_cast(unsigned, f);
  u += 0x7fffu + ((u >> 16) & 1u);
  return (ushort)(u >> 16);
}
__device__ __forceinline__ float b2f(ushort h) {
  return __builtin_bit_cast(float, ((unsigned)h) << 16);
}
// byte offset into a [rows][128B] LDS tile, XOR-swizzled (G4)
__device__ __forceinline__ int swz128(int row, int byteoff) {
  return row * 128 + (byteoff ^ ((row & 7) << 4));
}

// ---------------- prep: converts + rope tables ----------------
__global__ void prep_kernel(const float* __restrict__ x, const float* __restrict__ Wq,
                            const float* __restrict__ Wk, const float* __restrict__ Wv,
                            const float* __restrict__ Wo,
                            ushort* __restrict__ xb, ushort* __restrict__ w1,
                            ushort* __restrict__ wob,
                            float* __restrict__ cosT, float* __restrict__ sinT) {
  unsigned i = blockIdx.x * 256u + threadIdx.x;
  if (i < 2097152u) { xb[i] = f2b(x[i]); return; }
  if (i < 5242880u) {
    unsigned j = i - 2097152u;
    float v = (j < 1048576u) ? Wq[j] : (j < 2097152u ? Wk[j - 1048576u] : Wv[j - 2097152u]);
    w1[j] = f2b(v); return;
  }
  if (i < 6291456u) { unsigned j = i - 5242880u; wob[j] = f2b(Wo[j]); return; }
  unsigned j = i - 6291456u;           // 0..32767 : 2048 positions x 16 freqs
  int tt = (int)(j >> 4), jj = (int)(j & 15u);
  float inv = powf(10000.0f, -(float)(2 * jj) * (1.0f / 32.0f));
  float ang = (float)tt * inv;
  cosT[j] = cosf(ang);
  sinT[j] = sinf(ang);
}

// ---------------- rope (in-place on q,k halves of qkv) ----------------
__global__ void rope_kernel(ushort* __restrict__ qkv, const float* __restrict__ cosT,
                            const float* __restrict__ sinT) {
  unsigned i = blockIdx.x * 256u + threadIdx.x;  // 2M pairs
  int row = (int)(i >> 10), u = (int)(i & 1023u);
  int col = (u < 512) ? (2 * u) : (1024 + 2 * (u - 512));
  int j = u & 15;
  float c = cosT[row * 16 + j], s = sinT[row * 16 + j];
  unsigned v = *(const unsigned*)(qkv + (size_t)row * 3072 + col);
  float x1 = b2f((ushort)(v & 0xffffu));
  float x2 = b2f((ushort)(v >> 16));
  float ye = x1 * c - x2 * s;
  float yo = x1 * s + x2 * c;
  unsigned o = (unsigned)f2b(ye) | ((unsigned)f2b(yo) << 16);
  *(unsigned*)(qkv + (size_t)row * 3072 + col) = o;
}

// ---------------- transpose v -> vt[d][s] ----------------
__global__ __launch_bounds__(256) void transv_kernel(const ushort* __restrict__ qkv,
                                                     ushort* __restrict__ vt) {
  __shared__ __align__(16) ushort tile[64][80];
  const int t = threadIdx.x;
  const int d0 = blockIdx.x * 64, s0 = blockIdx.y * 64;
#pragma unroll
  for (int p = 0; p < 2; ++p) {
    int sl = p * 32 + (t >> 3), d8 = (t & 7) * 8;
    uint4 v = *(const uint4*)(qkv + (size_t)(s0 + sl) * 3072 + 2048 + d0 + d8);
    *(uint4*)(&tile[sl][d8]) = v;
  }
  __syncthreads();
#pragma unroll
  for (int p = 0; p < 2; ++p) {
    int dl = p * 32 + (t >> 3), s8 = (t & 7) * 8;
    union { ushort h[8]; uint4 u; } tmp;
#pragma unroll
    for (int jj = 0; jj < 8; ++jj) tmp.h[jj] = tile[s8 + jj][dl];
    *(uint4*)(vt + (size_t)(d0 + dl) * 2048 + s0 + s8) = tmp.u;
  }
}

// ---------------- GEMM: C[M,N] = A[M,K] . B[N,K]^T (m97-family 128x128 tile) ----------------
__global__ __launch_bounds__(256) void gemm_bt(const ushort* __restrict__ A,
                                               const ushort* __restrict__ B,
                                               void* __restrict__ C, int M, int N, int K,
                                               int out_bf16) {
  __shared__ __align__(16) ushort As[128 * 40];  // BK=32, padded to 40 (bank spread)
  __shared__ __align__(16) ushort Bs[128 * 40];
  const int t = threadIdx.x, lane = t & 63, w = t >> 6;
  const int g = lane >> 4, r = lane & 15;
  const int wr = w >> 1, wc = w & 1;
  const int m0 = blockIdx.y * 128, n0 = blockIdx.x * 128;

  f32x4 acc[4][4];
#pragma unroll
  for (int i = 0; i < 4; ++i)
#pragma unroll
    for (int j = 0; j < 4; ++j) acc[i][j] = (f32x4){0.f, 0.f, 0.f, 0.f};

  for (int k0 = 0; k0 < K; k0 += 32) {
    __syncthreads();
#pragma unroll
    for (int p = 0; p < 2; ++p) {
      int c = p * 256 + t;
      int row = c >> 2, ko = (c & 3) * 8;
      uint4 va = *(const uint4*)(A + (size_t)(m0 + row) * K + k0 + ko);
      uint4 vb = *(const uint4*)(B + (size_t)(n0 + row) * K + k0 + ko);
      *(uint4*)(As + row * 40 + ko) = va;
      *(uint4*)(Bs + row * 40 + ko) = vb;
    }
    __syncthreads();
    bf16x8 af[4], bfr[4];
#pragma unroll
    for (int i = 0; i < 4; ++i) {
      af[i] = __builtin_bit_cast(bf16x8, *(const uint4*)(As + (wr * 64 + i * 16 + r) * 40 + g * 8));
      bfr[i] = __builtin_bit_cast(bf16x8, *(const uint4*)(Bs + (wc * 64 + i * 16 + r) * 40 + g * 8));
    }
#pragma unroll
    for (int mi = 0; mi < 4; ++mi)
#pragma unroll
      for (int ni = 0; ni < 4; ++ni)
        acc[mi][ni] = __builtin_amdgcn_mfma_f32_16x16x32_bf16(af[mi], bfr[ni], acc[mi][ni], 0, 0, 0);
  }
#pragma unroll
  for (int mi = 0; mi < 4; ++mi)
#pragma unroll
    for (int ni = 0; ni < 4; ++ni)
#pragma unroll
      for (int e = 0; e < 4; ++e) {
        int row = m0 + wr * 64 + mi * 16 + g * 4 + e;
        int col = n0 + wc * 64 + ni * 16 + r;
        float v = acc[mi][ni][e];
        if (out_bf16) ((ushort*)C)[(size_t)row * N + col] = f2b(v);
        else ((float*)C)[(size_t)row * N + col] = v;
      }
}

// ---------------- fused differential flash attention ----------------
// block = (q-tile of 64 rows, head). 4 waves x 16 q-rows. Both subs computed
// together sharing K/V LDS tiles; epilogue fuses diff + RMSNorm + scale.
__global__ __launch_bounds__(256) void attn_kernel(
    const ushort* __restrict__ qkv, const ushort* __restrict__ vt,
    const float* __restrict__ lq1, const float* __restrict__ lk1,
    const float* __restrict__ lq2, const float* __restrict__ lk2,
    const float* __restrict__ gamma, ushort* __restrict__ attn_out) {
  __shared__ __align__(16) ushort Ks[64 * 64];      // [s][64ch k1|k2], swizzled
  __shared__ __align__(16) ushort Vs[64 * 64];      // vt tile [d][s], swizzled
  __shared__ __align__(16) ushort Ps[4 * 2 * 1024]; // per-wave, per-sub P [16][64]

  const int qt = blockIdx.x, h = blockIdx.y;
  const int t = threadIdx.x, lane = t & 63, w = t >> 6;
  const int g = lane >> 4, r = lane & 15;

  // lambda = exp(lq1.lk1) - exp(lq2.lk2) + LAM_INIT  (32-elem dots, wave reduce)
  float lam;
  {
    int d = lane & 31;
    float a1 = lq1[d] * lk1[d];
    float a2 = lq2[d] * lk2[d];
#pragma unroll
    for (int m = 16; m >= 1; m >>= 1) {
      a1 += __shfl_xor(a1, m);
      a2 += __shfl_xor(a2, m);
    }
    lam = expf(a1) - expf(a2) + LAM_INIT;
  }

  const int qrow0 = qt * 64 + w * 16;
  bf16x8 q1f = __builtin_bit_cast(bf16x8, *(const uint4*)(qkv + (size_t)(qrow0 + r) * 3072 + h * 64 + g * 8));
  bf16x8 q2f = __builtin_bit_cast(bf16x8, *(const uint4*)(qkv + (size_t)(qrow0 + r) * 3072 + h * 64 + 32 + g * 8));

  f32x4 O[2][4];
  float mm[2][4], ll[2][4];
#pragma unroll
  for (int sub = 0; sub < 2; ++sub)
#pragma unroll
    for (int e = 0; e < 4; ++e) {
      mm[sub][e] = -1e30f;
      ll[sub][e] = 0.f;
      O[sub][e] = (f32x4){0.f, 0.f, 0.f, 0.f};
    }

  for (int kt = 0; kt <= qt; ++kt) {
    __syncthreads();  // previous iter's LDS reads done
#pragma unroll
    for (int p = 0; p < 2; ++p) {
      int c = p * 256 + t;
      int row = c >> 3, c8 = (c & 7) * 8;
      uint4 kv = *(const uint4*)(qkv + (size_t)(kt * 64 + row) * 3072 + 1024 + h * 64 + c8);
      *(uint4*)((char*)Ks + swz128(row, c8 * 2)) = kv;
      uint4 vv = *(const uint4*)(vt + (size_t)(h * 64 + row) * 2048 + kt * 64 + c8);
      *(uint4*)((char*)Vs + swz128(row, c8 * 2)) = vv;
    }
    __syncthreads();

    // S = Q.K^T for both subs (one MFMA per 16x16 tile, K=32=hd)
    f32x4 sv[2][4];
    const f32x4 zz = {0.f, 0.f, 0.f, 0.f};
#pragma unroll
    for (int f = 0; f < 4; ++f) {
      int krow = f * 16 + r;
      bf16x8 k1f = __builtin_bit_cast(bf16x8, *(const uint4*)((const char*)Ks + swz128(krow, g * 16)));
      bf16x8 k2f = __builtin_bit_cast(bf16x8, *(const uint4*)((const char*)Ks + swz128(krow, 64 + g * 16)));
      sv[0][f] = __builtin_amdgcn_mfma_f32_16x16x32_bf16(q1f, k1f, zz, 0, 0, 0);
      sv[1][f] = __builtin_amdgcn_mfma_f32_16x16x32_bf16(q2f, k2f, zz, 0, 0, 0);
    }

    const bool diag = (kt == qt);
#pragma unroll
    for (int sub = 0; sub < 2; ++sub) {
      float rmax[4];
#pragma unroll
      for (int e = 0; e < 4; ++e) {
        float mx = -1e30f;
#pragma unroll
        for (int f = 0; f < 4; ++f) {
          float v = sv[sub][f][e] * SCALE;
          if (diag && (f * 16 + r) > (w * 16 + g * 4 + e)) v = -1e30f;  // causal
          sv[sub][f][e] = v;
          mx = fmaxf(mx, v);
        }
        rmax[e] = mx;
      }
#pragma unroll
      for (int d = 1; d <= 8; d <<= 1)
#pragma unroll
        for (int e = 0; e < 4; ++e) rmax[e] = fmaxf(rmax[e], __shfl_xor(rmax[e], d));
#pragma unroll
      for (int e = 0; e < 4; ++e) {
        float mn = fmaxf(mm[sub][e], rmax[e]);
        float es = exp2f((mm[sub][e] - mn) * LOG2E);
        mm[sub][e] = mn;
        float psum = 0.f;
#pragma unroll
        for (int f = 0; f < 4; ++f) {
          float p = exp2f((sv[sub][f][e] - mn) * LOG2E);
          sv[sub][f][e] = p;
          psum += p;
        }
#pragma unroll
        for (int d = 1; d <= 8; d <<= 1) psum += __shfl_xor(psum, d);
        ll[sub][e] = ll[sub][e] * es + psum;
#pragma unroll
        for (int cf = 0; cf < 4; ++cf) O[sub][cf][e] *= es;
      }
      // P -> LDS (bf16, swizzled), per-wave private region
      char* pb = (char*)Ps + (size_t)(w * 2 + sub) * 2048;
#pragma unroll
      for (int f = 0; f < 4; ++f)
#pragma unroll
        for (int e = 0; e < 4; ++e) {
          int prow = g * 4 + e, pcol = f * 16 + r;
          *(ushort*)(pb + swz128(prow, pcol * 2)) = f2b(sv[sub][f][e]);
        }
    }

    // PV: O[sub] += P[sub] . V   (V-frags shared between subs)
    char* pb0 = (char*)Ps + (size_t)(w * 2 + 0) * 2048;
    char* pb1 = (char*)Ps + (size_t)(w * 2 + 1) * 2048;
#pragma unroll
    for (int ks = 0; ks < 2; ++ks) {
      int cb = (ks * 32 + g * 8) * 2;
      bf16x8 pa0 = __builtin_bit_cast(bf16x8, *(const uint4*)(pb0 + swz128(r, cb)));
      bf16x8 pa1 = __builtin_bit_cast(bf16x8, *(const uint4*)(pb1 + swz128(r, cb)));
#pragma unroll
      for (int cf = 0; cf < 4; ++cf) {
        int vrow = cf * 16 + r;
        bf16x8 vf = __builtin_bit_cast(bf16x8, *(const uint4*)((const char*)Vs + swz128(vrow, cb)));
        O[0][cf] = __builtin_amdgcn_mfma_f32_16x16x32_bf16(pa0, vf, O[0][cf], 0, 0, 0);
        O[1][cf] = __builtin_amdgcn_mfma_f32_16x16x32_bf16(pa1, vf, O[1][cf], 0, 0, 0);
      }
    }
  }

  // epilogue: normalize by lsum, diff, RMSNorm over 64 ch, *gamma*(1-lam_init)
  float inv0[4], inv1[4];
#pragma unroll
  for (int e = 0; e < 4; ++e) {
    inv0[e] = 1.f / ll[0][e];
    inv1[e] = 1.f / ll[1][e];
  }
  float wv[4][4], ss[4] = {0.f, 0.f, 0.f, 0.f};
#pragma unroll
  for (int cf = 0; cf < 4; ++cf)
#pragma unroll
    for (int e = 0; e < 4; ++e) {
      float v = O[0][cf][e] * inv0[e] - lam * (O[1][cf][e] * inv1[e]);
      wv[cf][e] = v;
      ss[e] += v * v;
    }
#pragma unroll
  for (int d = 1; d <= 8; d <<= 1)
#pragma unroll
    for (int e = 0; e < 4; ++e) ss[e] += __shfl_xor(ss[e], d);
  float scl[4];
#pragma unroll
  for (int e = 0; e < 4; ++e) scl[e] = rsqrtf(ss[e] * (1.f / 64.f) + 1e-5f) * ONE_M_LI;
#pragma unroll
  for (int cf = 0; cf < 4; ++cf) {
    float gv = gamma[cf * 16 + r];
#pragma unroll
    for (int e = 0; e < 4; ++e) {
      float v = wv[cf][e] * scl[e] * gv;
      attn_out[(size_t)(qrow0 + g * 4 + e) * 1024 + h * 64 + cf * 16 + r] = f2b(v);
    }
  }
}

extern "C" void kernel_launch(void* const* d_in, const int* in_sizes, int n_in,
                              void* d_out, int out_size, void* d_ws, size_t ws_size,
                              hipStream_t stream) {
  const float* x = (const float*)d_in[0];
  const float* Wq = (const float*)d_in[1];
  const float* Wk = (const float*)d_in[2];
  const float* Wv = (const float*)d_in[3];
  const float* Wo = (const float*)d_in[4];
  const float* lq1 = (const float*)d_in[5];
  const float* lk1 = (const float*)d_in[6];
  const float* lq2 = (const float*)d_in[7];
  const float* lk2 = (const float*)d_in[8];
  const float* gamma = (const float*)d_in[9];
  (void)in_sizes; (void)n_in; (void)out_size; (void)ws_size;

  char* ws = (char*)d_ws;
  ushort* xb = (ushort*)(ws);
  ushort* w1 = (ushort*)(ws + (4ull << 20));
  ushort* wob = (ushort*)(ws + (10ull << 20));
  ushort* qkv = (ushort*)(ws + (12ull << 20));
  ushort* vt = (ushort*)(ws + (24ull << 20));
  ushort* atn = (ushort*)(ws + (28ull << 20));
  float* cosT = (float*)(ws + (32ull << 20));
  float* sinT = (float*)(ws + (32ull << 20) + 2048 * 16 * 4);

  prep_kernel<<<24704, 256, 0, stream>>>(x, Wq, Wk, Wv, Wo, xb, w1, wob, cosT, sinT);
  gemm_bt<<<dim3(24, 16), 256, 0, stream>>>(xb, w1, (void*)qkv, 2048, 3072, 1024, 1);
  rope_kernel<<<8192, 256, 0, stream>>>(qkv, cosT, sinT);
  transv_kernel<<<dim3(16, 32), 256, 0, stream>>>(qkv, vt);
  attn_kernel<<<dim3(32, 16), 256, 0, stream>>>(qkv, vt, lq1, lk1, lq2, lk2, gamma, atn);
  gemm_bt<<<dim3(8, 16), 256, 0, stream>>>(atn, wob, d_out, 2048, 1024, 1024, 0);
}

// Round 2
// 212.425 us; speedup vs baseline: 1.0070x; 1.0070x over previous
//
#include <hip/hip_runtime.h>
#include <hip/hip_bf16.h>
#include <math.h>

// Differential attention, bf16 MFMA pipeline, split-KV flash attention.
// ws layout (bytes):
//   [0,4M)    xb      x as bf16             2048x1024
//   [4M,10M)  w1      [Wq;Wk;Wv] bf16       3072x1024
//   [10M,12M) wob     Wo bf16               1024x1024
//   [12M,24M) qkv     bf16, row stride 3072 (q|k|v); rope applied in-place to q,k
//   [24M,28M) vt      v transposed bf16     1024x2048  vt[d][s]
//   [28M,32M) atn     normalized wv bf16    2048x1024
//   [32M,+256K) cos/sin tables fp32         2048x16 each
//   [33M, +40M)   pO   fp32 partial O   [1280 pids][2 subs][64 rows][64 ch]
//   [33M+40M,+1.25M) pML fp32 partial m,l [1280][2][2][64]
// pid = h*80 + qoff(qt) + chunk;  chunk = 512 kv rows (8 k-tiles of 64)

typedef __bf16 bf16x8 __attribute__((ext_vector_type(8)));
typedef float f32x4 __attribute__((ext_vector_type(4)));

#define LOG2E 1.4426950408889634f
#define SCALE 0.17677669529663687f /* 1/sqrt(32) */
#define LAM_INIT 0.783605766532f
#define ONE_M_LI 0.216394233468f

__device__ __forceinline__ ushort f2b(float f) {
  unsigned u = __builtin_bit_cast(unsigned, f);
  u += 0x7fffu + ((u >> 16) & 1u);
  return (ushort)(u >> 16);
}
__device__ __forceinline__ float b2f(ushort h) {
  return __builtin_bit_cast(float, ((unsigned)h) << 16);
}
// byte offset into a [rows][128B] LDS tile, XOR-swizzled (G4)
__device__ __forceinline__ int swz128(int row, int byteoff) {
  return row * 128 + (byteoff ^ ((row & 7) << 4));
}
// number of 512-row kv chunks for q-tile qt (64-row tiles): floor(qt/8)+1
// qoff = sum of chunk counts for q-tiles < qt
__device__ __forceinline__ int qoff(int qt) {
  int gg = qt >> 3;
  return ((gg * (gg + 1)) >> 1) * 8 + (qt & 7) * (gg + 1);
}

// ---------------- prep: converts + rope tables ----------------
__global__ void prep_kernel(const float* __restrict__ x, const float* __restrict__ Wq,
                            const float* __restrict__ Wk, const float* __restrict__ Wv,
                            const float* __restrict__ Wo,
                            ushort* __restrict__ xb, ushort* __restrict__ w1,
                            ushort* __restrict__ wob,
                            float* __restrict__ cosT, float* __restrict__ sinT) {
  unsigned i = blockIdx.x * 256u + threadIdx.x;
  if (i < 2097152u) { xb[i] = f2b(x[i]); return; }
  if (i < 5242880u) {
    unsigned j = i - 2097152u;
    float v = (j < 1048576u) ? Wq[j] : (j < 2097152u ? Wk[j - 1048576u] : Wv[j - 2097152u]);
    w1[j] = f2b(v); return;
  }
  if (i < 6291456u) { unsigned j = i - 5242880u; wob[j] = f2b(Wo[j]); return; }
  unsigned j = i - 6291456u;           // 0..32767 : 2048 positions x 16 freqs
  int tt = (int)(j >> 4), jj = (int)(j & 15u);
  float inv = powf(10000.0f, -(float)(2 * jj) * (1.0f / 32.0f));
  float ang = (float)tt * inv;
  cosT[j] = cosf(ang);
  sinT[j] = sinf(ang);
}

// ---------------- rope (in-place on q,k halves of qkv) ----------------
__global__ void rope_kernel(ushort* __restrict__ qkv, const float* __restrict__ cosT,
                            const float* __restrict__ sinT) {
  unsigned i = blockIdx.x * 256u + threadIdx.x;  // 2M pairs
  int row = (int)(i >> 10), u = (int)(i & 1023u);
  int col = (u < 512) ? (2 * u) : (1024 + 2 * (u - 512));
  int j = u & 15;
  float c = cosT[row * 16 + j], s = sinT[row * 16 + j];
  unsigned v = *(const unsigned*)(qkv + (size_t)row * 3072 + col);
  float x1 = b2f((ushort)(v & 0xffffu));
  float x2 = b2f((ushort)(v >> 16));
  float ye = x1 * c - x2 * s;
  float yo = x1 * s + x2 * c;
  unsigned o = (unsigned)f2b(ye) | ((unsigned)f2b(yo) << 16);
  *(unsigned*)(qkv + (size_t)row * 3072 + col) = o;
}

// ---------------- transpose v -> vt[d][s] ----------------
__global__ __launch_bounds__(256) void transv_kernel(const ushort* __restrict__ qkv,
                                                     ushort* __restrict__ vt) {
  __shared__ __align__(16) ushort tile[64][80];
  const int t = threadIdx.x;
  const int d0 = blockIdx.x * 64, s0 = blockIdx.y * 64;
#pragma unroll
  for (int p = 0; p < 2; ++p) {
    int sl = p * 32 + (t >> 3), d8 = (t & 7) * 8;
    uint4 v = *(const uint4*)(qkv + (size_t)(s0 + sl) * 3072 + 2048 + d0 + d8);
    *(uint4*)(&tile[sl][d8]) = v;
  }
  __syncthreads();
#pragma unroll
  for (int p = 0; p < 2; ++p) {
    int dl = p * 32 + (t >> 3), s8 = (t & 7) * 8;
    union { ushort h[8]; uint4 u; } tmp;
#pragma unroll
    for (int jj = 0; jj < 8; ++jj) tmp.h[jj] = tile[s8 + jj][dl];
    *(uint4*)(vt + (size_t)(d0 + dl) * 2048 + s0 + s8) = tmp.u;
  }
}

// ---------------- GEMM: C[M,N] = A[M,K] . B[N,K]^T (m97-family 128x128 tile) ----------------
__global__ __launch_bounds__(256) void gemm_bt(const ushort* __restrict__ A,
                                               const ushort* __restrict__ B,
                                               void* __restrict__ C, int M, int N, int K,
                                               int out_bf16) {
  __shared__ __align__(16) ushort As[128 * 40];  // BK=32, padded to 40 (bank spread)
  __shared__ __align__(16) ushort Bs[128 * 40];
  const int t = threadIdx.x, lane = t & 63, w = t >> 6;
  const int g = lane >> 4, r = lane & 15;
  const int wr = w >> 1, wc = w & 1;
  const int m0 = blockIdx.y * 128, n0 = blockIdx.x * 128;

  f32x4 acc[4][4];
#pragma unroll
  for (int i = 0; i < 4; ++i)
#pragma unroll
    for (int j = 0; j < 4; ++j) acc[i][j] = (f32x4){0.f, 0.f, 0.f, 0.f};

  for (int k0 = 0; k0 < K; k0 += 32) {
    __syncthreads();
#pragma unroll
    for (int p = 0; p < 2; ++p) {
      int c = p * 256 + t;
      int row = c >> 2, ko = (c & 3) * 8;
      uint4 va = *(const uint4*)(A + (size_t)(m0 + row) * K + k0 + ko);
      uint4 vb = *(const uint4*)(B + (size_t)(n0 + row) * K + k0 + ko);
      *(uint4*)(As + row * 40 + ko) = va;
      *(uint4*)(Bs + row * 40 + ko) = vb;
    }
    __syncthreads();
    bf16x8 af[4], bfr[4];
#pragma unroll
    for (int i = 0; i < 4; ++i) {
      af[i] = __builtin_bit_cast(bf16x8, *(const uint4*)(As + (wr * 64 + i * 16 + r) * 40 + g * 8));
      bfr[i] = __builtin_bit_cast(bf16x8, *(const uint4*)(Bs + (wc * 64 + i * 16 + r) * 40 + g * 8));
    }
#pragma unroll
    for (int mi = 0; mi < 4; ++mi)
#pragma unroll
      for (int ni = 0; ni < 4; ++ni)
        acc[mi][ni] = __builtin_amdgcn_mfma_f32_16x16x32_bf16(af[mi], bfr[ni], acc[mi][ni], 0, 0, 0);
  }
#pragma unroll
  for (int mi = 0; mi < 4; ++mi)
#pragma unroll
    for (int ni = 0; ni < 4; ++ni)
#pragma unroll
      for (int e = 0; e < 4; ++e) {
        int row = m0 + wr * 64 + mi * 16 + g * 4 + e;
        int col = n0 + wc * 64 + ni * 16 + r;
        float v = acc[mi][ni][e];
        if (out_bf16) ((ushort*)C)[(size_t)row * N + col] = f2b(v);
        else ((float*)C)[(size_t)row * N + col] = v;
      }
}

// ---------------- split-KV flash attention: partials ----------------
// block = (work-index -> (qt, chunk), head). 4 waves x 16 q-rows.
// Processes kv tiles [c*8, min(c*8+8, qt+1)), writes raw (m,l,O) partials.
__global__ __launch_bounds__(256) void attn_split_kernel(
    const ushort* __restrict__ qkv, const ushort* __restrict__ vt,
    float* __restrict__ pO, float* __restrict__ pML) {
  __shared__ __align__(16) ushort Ks[64 * 64];      // [s][64ch k1|k2], swizzled
  __shared__ __align__(16) ushort Vs[64 * 64];      // vt tile [d][s], swizzled
  __shared__ __align__(16) ushort Ps[4 * 2 * 1024]; // per-wave, per-sub P [16][64]

  // decode blockIdx.x in [0,80) -> (qt, c)
  int wi = blockIdx.x, qt = 0, c = 0;
  for (int q = 0; q < 32; ++q) {
    int nc = (q >> 3) + 1;
    if (wi < nc) { qt = q; c = wi; break; }
    wi -= nc;
  }
  const int h = blockIdx.y;
  const int pid = h * 80 + qoff(qt) + c;
  const int t = threadIdx.x, lane = t & 63, w = t >> 6;
  const int g = lane >> 4, r = lane & 15;

  const int qrow0 = qt * 64 + w * 16;
  bf16x8 q1f = __builtin_bit_cast(bf16x8, *(const uint4*)(qkv + (size_t)(qrow0 + r) * 3072 + h * 64 + g * 8));
  bf16x8 q2f = __builtin_bit_cast(bf16x8, *(const uint4*)(qkv + (size_t)(qrow0 + r) * 3072 + h * 64 + 32 + g * 8));

  f32x4 O[2][4];
  float mm[2][4], ll[2][4];
#pragma unroll
  for (int sub = 0; sub < 2; ++sub)
#pragma unroll
    for (int e = 0; e < 4; ++e) {
      mm[sub][e] = -1e30f;
      ll[sub][e] = 0.f;
      O[sub][e] = (f32x4){0.f, 0.f, 0.f, 0.f};
    }

  const int ktb = c * 8;
  const int kte = min(ktb + 8, qt + 1);
  for (int kt = ktb; kt < kte; ++kt) {
    __syncthreads();  // previous iter's LDS reads done
#pragma unroll
    for (int p = 0; p < 2; ++p) {
      int cc = p * 256 + t;
      int row = cc >> 3, c8 = (cc & 7) * 8;
      uint4 kv = *(const uint4*)(qkv + (size_t)(kt * 64 + row) * 3072 + 1024 + h * 64 + c8);
      *(uint4*)((char*)Ks + swz128(row, c8 * 2)) = kv;
      uint4 vv = *(const uint4*)(vt + (size_t)(h * 64 + row) * 2048 + kt * 64 + c8);
      *(uint4*)((char*)Vs + swz128(row, c8 * 2)) = vv;
    }
    __syncthreads();

    // S = Q.K^T for both subs (one MFMA per 16x16 tile, K=32=hd)
    f32x4 sv[2][4];
    const f32x4 zz = {0.f, 0.f, 0.f, 0.f};
#pragma unroll
    for (int f = 0; f < 4; ++f) {
      int krow = f * 16 + r;
      bf16x8 k1f = __builtin_bit_cast(bf16x8, *(const uint4*)((const char*)Ks + swz128(krow, g * 16)));
      bf16x8 k2f = __builtin_bit_cast(bf16x8, *(const uint4*)((const char*)Ks + swz128(krow, 64 + g * 16)));
      sv[0][f] = __builtin_amdgcn_mfma_f32_16x16x32_bf16(q1f, k1f, zz, 0, 0, 0);
      sv[1][f] = __builtin_amdgcn_mfma_f32_16x16x32_bf16(q2f, k2f, zz, 0, 0, 0);
    }

    const bool diag = (kt == qt);
#pragma unroll
    for (int sub = 0; sub < 2; ++sub) {
      float rmax[4];
#pragma unroll
      for (int e = 0; e < 4; ++e) {
        float mx = -1e30f;
#pragma unroll
        for (int f = 0; f < 4; ++f) {
          float v = sv[sub][f][e] * SCALE;
          if (diag && (f * 16 + r) > (w * 16 + g * 4 + e)) v = -1e30f;  // causal
          sv[sub][f][e] = v;
          mx = fmaxf(mx, v);
        }
        rmax[e] = mx;
      }
#pragma unroll
      for (int d = 1; d <= 8; d <<= 1)
#pragma unroll
        for (int e = 0; e < 4; ++e) rmax[e] = fmaxf(rmax[e], __shfl_xor(rmax[e], d));
#pragma unroll
      for (int e = 0; e < 4; ++e) {
        float mn = fmaxf(mm[sub][e], rmax[e]);
        float es = exp2f((mm[sub][e] - mn) * LOG2E);
        mm[sub][e] = mn;
        float psum = 0.f;
#pragma unroll
        for (int f = 0; f < 4; ++f) {
          float p = exp2f((sv[sub][f][e] - mn) * LOG2E);
          sv[sub][f][e] = p;
          psum += p;
        }
#pragma unroll
        for (int d = 1; d <= 8; d <<= 1) psum += __shfl_xor(psum, d);
        ll[sub][e] = ll[sub][e] * es + psum;
#pragma unroll
        for (int cf = 0; cf < 4; ++cf) O[sub][cf][e] *= es;
      }
      // P -> LDS (bf16, swizzled), per-wave private region
      char* pb = (char*)Ps + (size_t)(w * 2 + sub) * 2048;
#pragma unroll
      for (int f = 0; f < 4; ++f)
#pragma unroll
        for (int e = 0; e < 4; ++e) {
          int prow = g * 4 + e, pcol = f * 16 + r;
          *(ushort*)(pb + swz128(prow, pcol * 2)) = f2b(sv[sub][f][e]);
        }
    }

    // PV: O[sub] += P[sub] . V   (V-frags shared between subs)
    char* pb0 = (char*)Ps + (size_t)(w * 2 + 0) * 2048;
    char* pb1 = (char*)Ps + (size_t)(w * 2 + 1) * 2048;
#pragma unroll
    for (int ks = 0; ks < 2; ++ks) {
      int cb = (ks * 32 + g * 8) * 2;
      bf16x8 pa0 = __builtin_bit_cast(bf16x8, *(const uint4*)(pb0 + swz128(r, cb)));
      bf16x8 pa1 = __builtin_bit_cast(bf16x8, *(const uint4*)(pb1 + swz128(r, cb)));
#pragma unroll
      for (int cf = 0; cf < 4; ++cf) {
        int vrow = cf * 16 + r;
        bf16x8 vf = __builtin_bit_cast(bf16x8, *(const uint4*)((const char*)Vs + swz128(vrow, cb)));
        O[0][cf] = __builtin_amdgcn_mfma_f32_16x16x32_bf16(pa0, vf, O[0][cf], 0, 0, 0);
        O[1][cf] = __builtin_amdgcn_mfma_f32_16x16x32_bf16(pa1, vf, O[1][cf], 0, 0, 0);
      }
    }
  }

  // write raw partials (no per-row divide)
#pragma unroll
  for (int sub = 0; sub < 2; ++sub) {
    if (r == 0) {
#pragma unroll
      for (int e = 0; e < 4; ++e) {
        int row = w * 16 + g * 4 + e;
        pML[(size_t)pid * 256 + sub * 128 + row] = mm[sub][e];
        pML[(size_t)pid * 256 + sub * 128 + 64 + row] = ll[sub][e];
      }
    }
#pragma unroll
    for (int cf = 0; cf < 4; ++cf)
#pragma unroll
      for (int e = 0; e < 4; ++e) {
        int row = w * 16 + g * 4 + e;
        pO[((size_t)(pid * 2 + sub) * 64 + row) * 64 + cf * 16 + r] = O[sub][cf][e];
      }
  }
}

// ---------------- combine partials + diff + RMSNorm ----------------
// block = (qt, h), 256 threads: thread t -> row = t>>2, quad = t&3 (16 ch each)
__global__ __launch_bounds__(256) void combine_kernel(
    const float* __restrict__ pO, const float* __restrict__ pML,
    const float* __restrict__ lq1, const float* __restrict__ lk1,
    const float* __restrict__ lq2, const float* __restrict__ lk2,
    const float* __restrict__ gamma, ushort* __restrict__ attn_out) {
  const int qt = blockIdx.x, h = blockIdx.y;
  const int nc = (qt >> 3) + 1;
  const int pbase = h * 80 + qoff(qt);
  const int t = threadIdx.x, row = t >> 2, quad = t & 3;
  const int lane = t & 63;

  // lambda = exp(lq1.lk1) - exp(lq2.lk2) + LAM_INIT
  float lam;
  {
    int d = lane & 31;
    float a1 = lq1[d] * lk1[d];
    float a2 = lq2[d] * lk2[d];
#pragma unroll
    for (int m = 16; m >= 1; m >>= 1) {
      a1 += __shfl_xor(a1, m);
      a2 += __shfl_xor(a2, m);
    }
    lam = expf(a1) - expf(a2) + LAM_INIT;
  }

  float M[2] = {-1e30f, -1e30f};
  for (int c = 0; c < nc; ++c) {
    const float* ml = pML + (size_t)(pbase + c) * 256;
    M[0] = fmaxf(M[0], ml[row]);
    M[1] = fmaxf(M[1], ml[128 + row]);
  }
  float L[2] = {0.f, 0.f};
  f32x4 acc[2][4];
#pragma unroll
  for (int s = 0; s < 2; ++s)
#pragma unroll
    for (int v = 0; v < 4; ++v) acc[s][v] = (f32x4){0.f, 0.f, 0.f, 0.f};

  for (int c = 0; c < nc; ++c) {
    const int pid = pbase + c;
    const float* ml = pML + (size_t)pid * 256;
#pragma unroll
    for (int s = 0; s < 2; ++s) {
      float mc = ml[s * 128 + row];
      float lc = ml[s * 128 + 64 + row];
      float wgt = exp2f((mc - M[s]) * LOG2E);
      L[s] += lc * wgt;
      const f32x4* op = (const f32x4*)(pO + ((size_t)(pid * 2 + s) * 64 + row) * 64 + quad * 16);
#pragma unroll
      for (int v = 0; v < 4; ++v) {
        f32x4 x = op[v];
        acc[s][v] += x * wgt;
      }
    }
  }

  float inv0 = 1.f / L[0], inv1 = 1.f / L[1];
  float wv[16], ss = 0.f;
#pragma unroll
  for (int v = 0; v < 4; ++v)
#pragma unroll
    for (int e = 0; e < 4; ++e) {
      float val = acc[0][v][e] * inv0 - lam * (acc[1][v][e] * inv1);
      wv[v * 4 + e] = val;
      ss += val * val;
    }
  ss += __shfl_xor(ss, 1);
  ss += __shfl_xor(ss, 2);
  float scl = rsqrtf(ss * (1.f / 64.f) + 1e-5f) * ONE_M_LI;

  union { ushort hs[16]; uint4 u[2]; } outp;
#pragma unroll
  for (int j = 0; j < 16; ++j)
    outp.hs[j] = f2b(wv[j] * scl * gamma[quad * 16 + j]);
  uint4* dst = (uint4*)(attn_out + (size_t)(qt * 64 + row) * 1024 + h * 64 + quad * 16);
  dst[0] = outp.u[0];
  dst[1] = outp.u[1];
}

// ---------------- fallback: single-pass fused attention (R1 version) ----------------
__global__ __launch_bounds__(256) void attn_kernel(
    const ushort* __restrict__ qkv, const ushort* __restrict__ vt,
    const float* __restrict__ lq1, const float* __restrict__ lk1,
    const float* __restrict__ lq2, const float* __restrict__ lk2,
    const float* __restrict__ gamma, ushort* __restrict__ attn_out) {
  __shared__ __align__(16) ushort Ks[64 * 64];
  __shared__ __align__(16) ushort Vs[64 * 64];
  __shared__ __align__(16) ushort Ps[4 * 2 * 1024];

  const int qt = blockIdx.x, h = blockIdx.y;
  const int t = threadIdx.x, lane = t & 63, w = t >> 6;
  const int g = lane >> 4, r = lane & 15;

  float lam;
  {
    int d = lane & 31;
    float a1 = lq1[d] * lk1[d];
    float a2 = lq2[d] * lk2[d];
#pragma unroll
    for (int m = 16; m >= 1; m >>= 1) {
      a1 += __shfl_xor(a1, m);
      a2 += __shfl_xor(a2, m);
    }
    lam = expf(a1) - expf(a2) + LAM_INIT;
  }

  const int qrow0 = qt * 64 + w * 16;
  bf16x8 q1f = __builtin_bit_cast(bf16x8, *(const uint4*)(qkv + (size_t)(qrow0 + r) * 3072 + h * 64 + g * 8));
  bf16x8 q2f = __builtin_bit_cast(bf16x8, *(const uint4*)(qkv + (size_t)(qrow0 + r) * 3072 + h * 64 + 32 + g * 8));

  f32x4 O[2][4];
  float mm[2][4], ll[2][4];
#pragma unroll
  for (int sub = 0; sub < 2; ++sub)
#pragma unroll
    for (int e = 0; e < 4; ++e) {
      mm[sub][e] = -1e30f;
      ll[sub][e] = 0.f;
      O[sub][e] = (f32x4){0.f, 0.f, 0.f, 0.f};
    }

  for (int kt = 0; kt <= qt; ++kt) {
    __syncthreads();
#pragma unroll
    for (int p = 0; p < 2; ++p) {
      int cc = p * 256 + t;
      int row = cc >> 3, c8 = (cc & 7) * 8;
      uint4 kv = *(const uint4*)(qkv + (size_t)(kt * 64 + row) * 3072 + 1024 + h * 64 + c8);
      *(uint4*)((char*)Ks + swz128(row, c8 * 2)) = kv;
      uint4 vv = *(const uint4*)(vt + (size_t)(h * 64 + row) * 2048 + kt * 64 + c8);
      *(uint4*)((char*)Vs + swz128(row, c8 * 2)) = vv;
    }
    __syncthreads();

    f32x4 sv[2][4];
    const f32x4 zz = {0.f, 0.f, 0.f, 0.f};
#pragma unroll
    for (int f = 0; f < 4; ++f) {
      int krow = f * 16 + r;
      bf16x8 k1f = __builtin_bit_cast(bf16x8, *(const uint4*)((const char*)Ks + swz128(krow, g * 16)));
      bf16x8 k2f = __builtin_bit_cast(bf16x8, *(const uint4*)((const char*)Ks + swz128(krow, 64 + g * 16)));
      sv[0][f] = __builtin_amdgcn_mfma_f32_16x16x32_bf16(q1f, k1f, zz, 0, 0, 0);
      sv[1][f] = __builtin_amdgcn_mfma_f32_16x16x32_bf16(q2f, k2f, zz, 0, 0, 0);
    }

    const bool diag = (kt == qt);
#pragma unroll
    for (int sub = 0; sub < 2; ++sub) {
      float rmax[4];
#pragma unroll
      for (int e = 0; e < 4; ++e) {
        float mx = -1e30f;
#pragma unroll
        for (int f = 0; f < 4; ++f) {
          float v = sv[sub][f][e] * SCALE;
          if (diag && (f * 16 + r) > (w * 16 + g * 4 + e)) v = -1e30f;
          sv[sub][f][e] = v;
          mx = fmaxf(mx, v);
        }
        rmax[e] = mx;
      }
#pragma unroll
      for (int d = 1; d <= 8; d <<= 1)
#pragma unroll
        for (int e = 0; e < 4; ++e) rmax[e] = fmaxf(rmax[e], __shfl_xor(rmax[e], d));
#pragma unroll
      for (int e = 0; e < 4; ++e) {
        float mn = fmaxf(mm[sub][e], rmax[e]);
        float es = exp2f((mm[sub][e] - mn) * LOG2E);
        mm[sub][e] = mn;
        float psum = 0.f;
#pragma unroll
        for (int f = 0; f < 4; ++f) {
          float p = exp2f((sv[sub][f][e] - mn) * LOG2E);
          sv[sub][f][e] = p;
          psum += p;
        }
#pragma unroll
        for (int d = 1; d <= 8; d <<= 1) psum += __shfl_xor(psum, d);
        ll[sub][e] = ll[sub][e] * es + psum;
#pragma unroll
        for (int cf = 0; cf < 4; ++cf) O[sub][cf][e] *= es;
      }
      char* pb = (char*)Ps + (size_t)(w * 2 + sub) * 2048;
#pragma unroll
      for (int f = 0; f < 4; ++f)
#pragma unroll
        for (int e = 0; e < 4; ++e) {
          int prow = g * 4 + e, pcol = f * 16 + r;
          *(ushort*)(pb + swz128(prow, pcol * 2)) = f2b(sv[sub][f][e]);
        }
    }

    char* pb0 = (char*)Ps + (size_t)(w * 2 + 0) * 2048;
    char* pb1 = (char*)Ps + (size_t)(w * 2 + 1) * 2048;
#pragma unroll
    for (int ks = 0; ks < 2; ++ks) {
      int cb = (ks * 32 + g * 8) * 2;
      bf16x8 pa0 = __builtin_bit_cast(bf16x8, *(const uint4*)(pb0 + swz128(r, cb)));
      bf16x8 pa1 = __builtin_bit_cast(bf16x8, *(const uint4*)(pb1 + swz128(r, cb)));
#pragma unroll
      for (int cf = 0; cf < 4; ++cf) {
        int vrow = cf * 16 + r;
        bf16x8 vf = __builtin_bit_cast(bf16x8, *(const uint4*)((const char*)Vs + swz128(vrow, cb)));
        O[0][cf] = __builtin_amdgcn_mfma_f32_16x16x32_bf16(pa0, vf, O[0][cf], 0, 0, 0);
        O[1][cf] = __builtin_amdgcn_mfma_f32_16x16x32_bf16(pa1, vf, O[1][cf], 0, 0, 0);
      }
    }
  }

  float inv0[4], inv1[4];
#pragma unroll
  for (int e = 0; e < 4; ++e) {
    inv0[e] = 1.f / ll[0][e];
    inv1[e] = 1.f / ll[1][e];
  }
  float wv[4][4], ss[4] = {0.f, 0.f, 0.f, 0.f};
#pragma unroll
  for (int cf = 0; cf < 4; ++cf)
#pragma unroll
    for (int e = 0; e < 4; ++e) {
      float v = O[0][cf][e] * inv0[e] - lam * (O[1][cf][e] * inv1[e]);
      wv[cf][e] = v;
      ss[e] += v * v;
    }
#pragma unroll
  for (int d = 1; d <= 8; d <<= 1)
#pragma unroll
    for (int e = 0; e < 4; ++e) ss[e] += __shfl_xor(ss[e], d);
  float scl[4];
#pragma unroll
  for (int e = 0; e < 4; ++e) scl[e] = rsqrtf(ss[e] * (1.f / 64.f) + 1e-5f) * ONE_M_LI;
#pragma unroll
  for (int cf = 0; cf < 4; ++cf) {
    float gv = gamma[cf * 16 + r];
#pragma unroll
    for (int e = 0; e < 4; ++e) {
      float v = wv[cf][e] * scl[e] * gv;
      attn_out[(size_t)(qrow0 + g * 4 + e) * 1024 + h * 64 + cf * 16 + r] = f2b(v);
    }
  }
}

extern "C" void kernel_launch(void* const* d_in, const int* in_sizes, int n_in,
                              void* d_out, int out_size, void* d_ws, size_t ws_size,
                              hipStream_t stream) {
  const float* x = (const float*)d_in[0];
  const float* Wq = (const float*)d_in[1];
  const float* Wk = (const float*)d_in[2];
  const float* Wv = (const float*)d_in[3];
  const float* Wo = (const float*)d_in[4];
  const float* lq1 = (const float*)d_in[5];
  const float* lk1 = (const float*)d_in[6];
  const float* lq2 = (const float*)d_in[7];
  const float* lk2 = (const float*)d_in[8];
  const float* gamma = (const float*)d_in[9];
  (void)in_sizes; (void)n_in; (void)out_size;

  char* ws = (char*)d_ws;
  ushort* xb = (ushort*)(ws);
  ushort* w1 = (ushort*)(ws + (4ull << 20));
  ushort* wob = (ushort*)(ws + (10ull << 20));
  ushort* qkv = (ushort*)(ws + (12ull << 20));
  ushort* vt = (ushort*)(ws + (24ull << 20));
  ushort* atn = (ushort*)(ws + (28ull << 20));
  float* cosT = (float*)(ws + (32ull << 20));
  float* sinT = (float*)(ws + (32ull << 20) + 2048 * 16 * 4);
  float* pO = (float*)(ws + (33ull << 20));
  float* pML = (float*)(ws + (33ull << 20) + 1280ull * 2 * 64 * 64 * 4);
  const size_t ws_needed = (33ull << 20) + 1280ull * 2 * 64 * 64 * 4 + 1280ull * 256 * 4;

  prep_kernel<<<24704, 256, 0, stream>>>(x, Wq, Wk, Wv, Wo, xb, w1, wob, cosT, sinT);
  gemm_bt<<<dim3(24, 16), 256, 0, stream>>>(xb, w1, (void*)qkv, 2048, 3072, 1024, 1);
  rope_kernel<<<8192, 256, 0, stream>>>(qkv, cosT, sinT);
  transv_kernel<<<dim3(16, 32), 256, 0, stream>>>(qkv, vt);
  if (ws_size >= ws_needed) {
    attn_split_kernel<<<dim3(80, 16), 256, 0, stream>>>(qkv, vt, pO, pML);
    combine_kernel<<<dim3(32, 16), 256, 0, stream>>>(pO, pML, lq1, lk1, lq2, lk2, gamma, atn);
  } else {
    attn_kernel<<<dim3(32, 16), 256, 0, stream>>>(qkv, vt, lq1, lk1, lq2, lk2, gamma, atn);
  }
  gemm_bt<<<dim3(8, 16), 256, 0, stream>>>(atn, wob, d_out, 2048, 1024, 1024, 0);
}

// Round 3
// 132.729 us; speedup vs baseline: 1.6116x; 1.6004x over previous
//
#include <hip/hip_runtime.h>
#include <hip/hip_bf16.h>
#include <math.h>

// Differential attention, bf16 MFMA pipeline, split-KV flash attention with
// swapped-operand 32x32x16 MFMA softmax (T12 structure: in-register P via
// cvt_pk_bf16 + permlane32_swap; O^T accumulation keeps q on lane&31).
// ws layout (bytes):
//   [0,4M)    xb      x as bf16             2048x1024
//   [4M,10M)  w1      [Wq;Wk;Wv] bf16       3072x1024
//   [10M,12M) wob     Wo bf16               1024x1024
//   [12M,24M) qkv     bf16, row stride 3072 (q|k|v); rope applied in-place to q,k
//   [24M,28M) vt      v transposed bf16     1024x2048  vt[d][s]
//   [28M,32M) atn     normalized wv bf16    2048x1024
//   [32M,+256K) cos/sin tables fp32         2048x16 each
//   [33M,+37.75M)  pOh  fp16 partial O  [2304 pids][2 subs][64 q][64 d]
//   [33M+37.75M,+2.36M) pML fp32 partial m,l [2304][2][2][64]
// pid = h*144 + qoff4(qt) + chunk;  chunk = 256 kv rows (4 k-tiles of 64)

typedef __bf16 bf16x8 __attribute__((ext_vector_type(8)));
typedef float f32x4 __attribute__((ext_vector_type(4)));
typedef float f32x16 __attribute__((ext_vector_type(16)));

#define LOG2E 1.4426950408889634f
#define SCALE 0.17677669529663687f /* 1/sqrt(32) */
#define C1EXP 0.25506100319239545f /* SCALE*LOG2E : exp2 scale for raw S */
#define LAM_INIT 0.783605766532f
#define ONE_M_LI 0.216394233468f

__device__ __forceinline__ ushort f2b(float f) {
  unsigned u = __builtin_bit_cast(unsigned, f);
  u += 0x7fffu + ((u >> 16) & 1u);
  return (ushort)(u >> 16);
}
__device__ __forceinline__ float b2f(ushort h) {
  return __builtin_bit_cast(float, ((unsigned)h) << 16);
}
__device__ __forceinline__ ushort f2h(float f) {
  _Float16 h = (_Float16)f;
  return __builtin_bit_cast(ushort, h);
}
__device__ __forceinline__ float h2f(ushort u) {
  return (float)__builtin_bit_cast(_Float16, u);
}
// byte offset into a [rows][128B] LDS tile, XOR-swizzled (G4)
__device__ __forceinline__ int swz128(int row, int byteoff) {
  return row * 128 + (byteoff ^ ((row & 7) << 4));
}
// chunk=4 tiles: #chunks for q-tile m-1.. ; qoff4(qt) = sum_{q<qt} ceil((q+1)/4)
__device__ __forceinline__ int qoff4(int qt) {
  int G = qt >> 2, rem = qt & 3;
  return 2 * G * (G + 1) + rem * (G + 1);
}
__device__ __forceinline__ f32x16 zero16() {
  f32x16 z;
#pragma unroll
  for (int i = 0; i < 16; ++i) z[i] = 0.f;
  return z;
}

// ---------------- prep: converts + rope tables ----------------
__global__ void prep_kernel(const float* __restrict__ x, const float* __restrict__ Wq,
                            const float* __restrict__ Wk, const float* __restrict__ Wv,
                            const float* __restrict__ Wo,
                            ushort* __restrict__ xb, ushort* __restrict__ w1,
                            ushort* __restrict__ wob,
                            float* __restrict__ cosT, float* __restrict__ sinT) {
  unsigned i = blockIdx.x * 256u + threadIdx.x;
  if (i < 2097152u) { xb[i] = f2b(x[i]); return; }
  if (i < 5242880u) {
    unsigned j = i - 2097152u;
    float v = (j < 1048576u) ? Wq[j] : (j < 2097152u ? Wk[j - 1048576u] : Wv[j - 2097152u]);
    w1[j] = f2b(v); return;
  }
  if (i < 6291456u) { unsigned j = i - 5242880u; wob[j] = f2b(Wo[j]); return; }
  unsigned j = i - 6291456u;           // 0..32767 : 2048 positions x 16 freqs
  int tt = (int)(j >> 4), jj = (int)(j & 15u);
  float inv = powf(10000.0f, -(float)(2 * jj) * (1.0f / 32.0f));
  float ang = (float)tt * inv;
  cosT[j] = cosf(ang);
  sinT[j] = sinf(ang);
}

// ---------------- rope (in-place on q,k halves of qkv) ----------------
__global__ void rope_kernel(ushort* __restrict__ qkv, const float* __restrict__ cosT,
                            const float* __restrict__ sinT) {
  unsigned i = blockIdx.x * 256u + threadIdx.x;  // 2M pairs
  int row = (int)(i >> 10), u = (int)(i & 1023u);
  int col = (u < 512) ? (2 * u) : (1024 + 2 * (u - 512));
  int j = u & 15;
  float c = cosT[row * 16 + j], s = sinT[row * 16 + j];
  unsigned v = *(const unsigned*)(qkv + (size_t)row * 3072 + col);
  float x1 = b2f((ushort)(v & 0xffffu));
  float x2 = b2f((ushort)(v >> 16));
  float ye = x1 * c - x2 * s;
  float yo = x1 * s + x2 * c;
  unsigned o = (unsigned)f2b(ye) | ((unsigned)f2b(yo) << 16);
  *(unsigned*)(qkv + (size_t)row * 3072 + col) = o;
}

// ---------------- transpose v -> vt[d][s] ----------------
__global__ __launch_bounds__(256) void transv_kernel(const ushort* __restrict__ qkv,
                                                     ushort* __restrict__ vt) {
  __shared__ __align__(16) ushort tile[64][80];
  const int t = threadIdx.x;
  const int d0 = blockIdx.x * 64, s0 = blockIdx.y * 64;
#pragma unroll
  for (int p = 0; p < 2; ++p) {
    int sl = p * 32 + (t >> 3), d8 = (t & 7) * 8;
    uint4 v = *(const uint4*)(qkv + (size_t)(s0 + sl) * 3072 + 2048 + d0 + d8);
    *(uint4*)(&tile[sl][d8]) = v;
  }
  __syncthreads();
#pragma unroll
  for (int p = 0; p < 2; ++p) {
    int dl = p * 32 + (t >> 3), s8 = (t & 7) * 8;
    union { ushort h[8]; uint4 u; } tmp;
#pragma unroll
    for (int jj = 0; jj < 8; ++jj) tmp.h[jj] = tile[s8 + jj][dl];
    *(uint4*)(vt + (size_t)(d0 + dl) * 2048 + s0 + s8) = tmp.u;
  }
}

// ---------------- GEMM: C[M,N] = A[M,K] . B[N,K]^T (m97-family 128x128 tile) ----------------
__global__ __launch_bounds__(256) void gemm_bt(const ushort* __restrict__ A,
                                               const ushort* __restrict__ B,
                                               void* __restrict__ C, int M, int N, int K,
                                               int out_bf16) {
  __shared__ __align__(16) ushort As[128 * 40];  // BK=32, padded to 40 (bank spread)
  __shared__ __align__(16) ushort Bs[128 * 40];
  const int t = threadIdx.x, lane = t & 63, w = t >> 6;
  const int g = lane >> 4, r = lane & 15;
  const int wr = w >> 1, wc = w & 1;
  const int m0 = blockIdx.y * 128, n0 = blockIdx.x * 128;

  f32x4 acc[4][4];
#pragma unroll
  for (int i = 0; i < 4; ++i)
#pragma unroll
    for (int j = 0; j < 4; ++j) acc[i][j] = (f32x4){0.f, 0.f, 0.f, 0.f};

  for (int k0 = 0; k0 < K; k0 += 32) {
    __syncthreads();
#pragma unroll
    for (int p = 0; p < 2; ++p) {
      int c = p * 256 + t;
      int row = c >> 2, ko = (c & 3) * 8;
      uint4 va = *(const uint4*)(A + (size_t)(m0 + row) * K + k0 + ko);
      uint4 vb = *(const uint4*)(B + (size_t)(n0 + row) * K + k0 + ko);
      *(uint4*)(As + row * 40 + ko) = va;
      *(uint4*)(Bs + row * 40 + ko) = vb;
    }
    __syncthreads();
    bf16x8 af[4], bfr[4];
#pragma unroll
    for (int i = 0; i < 4; ++i) {
      af[i] = __builtin_bit_cast(bf16x8, *(const uint4*)(As + (wr * 64 + i * 16 + r) * 40 + g * 8));
      bfr[i] = __builtin_bit_cast(bf16x8, *(const uint4*)(Bs + (wc * 64 + i * 16 + r) * 40 + g * 8));
    }
#pragma unroll
    for (int mi = 0; mi < 4; ++mi)
#pragma unroll
      for (int ni = 0; ni < 4; ++ni)
        acc[mi][ni] = __builtin_amdgcn_mfma_f32_16x16x32_bf16(af[mi], bfr[ni], acc[mi][ni], 0, 0, 0);
  }
#pragma unroll
  for (int mi = 0; mi < 4; ++mi)
#pragma unroll
    for (int ni = 0; ni < 4; ++ni)
#pragma unroll
      for (int e = 0; e < 4; ++e) {
        int row = m0 + wr * 64 + mi * 16 + g * 4 + e;
        int col = n0 + wc * 64 + ni * 16 + r;
        float v = acc[mi][ni][e];
        if (out_bf16) ((ushort*)C)[(size_t)row * N + col] = f2b(v);
        else ((float*)C)[(size_t)row * N + col] = v;
      }
}

// ---------------- split-KV flash attention: 32x32 swapped-operand partials ----------------
// block = (work->(qt, chunk), head). 4 waves: wave w: sub = w&1, qhalf = w>>1.
// Each wave: 32 q-rows (q = lane&31), one sub, full 64 output d-channels.
// S^T = mfma(K, Q): lane holds P-column for its q-row -> in-lane softmax.
// P packed to bf16 in-register (cvt_pk + permlane32_swap), O^T = mfma(V^T, P).
__global__ __launch_bounds__(256, 3) void attn_split_kernel(
    const ushort* __restrict__ qkv, const ushort* __restrict__ vt,
    ushort* __restrict__ pOh, float* __restrict__ pML) {
  __shared__ __align__(16) ushort Ks[64 * 64];  // [kv row][64ch k1|k2], swizzled
  __shared__ __align__(16) ushort Vs[64 * 64];  // vt tile [d][kv], swizzled

  // decode blockIdx.x in [0,144) -> (qt, c)
  int wi = blockIdx.x, qt = 0, c = 0;
  for (int q = 0; q < 32; ++q) {
    int nc = (q >> 2) + 1;
    if (wi < nc) { qt = q; c = wi; break; }
    wi -= nc;
  }
  const int h = blockIdx.y;
  const int pid = h * 144 + qoff4(qt) + c;
  const int t = threadIdx.x, lane = t & 63, w = t >> 6;
  const int sub = w & 1, qh = w >> 1;
  const int ql = lane & 31, g1 = lane >> 5;
  const int qa = qt * 64 + qh * 32 + ql;  // absolute q row for this lane

  // Q as B-operand: B[q=lane&31][ch = chain*16 + g1*8 + j]
  bf16x8 qf0 = __builtin_bit_cast(bf16x8, *(const uint4*)(qkv + (size_t)qa * 3072 + h * 64 + sub * 32 + g1 * 8));
  bf16x8 qf1 = __builtin_bit_cast(bf16x8, *(const uint4*)(qkv + (size_t)qa * 3072 + h * 64 + sub * 32 + 16 + g1 * 8));

  f32x16 O0 = zero16(), O1 = zero16();  // O^T[d = dblk*32 + rowmap][q = lane&31]
  float mm = -1e30f, lsum = 0.f;

  const int ktb = c * 4;
  const int kte = min(ktb + 4, qt + 1);
  for (int kt = ktb; kt < kte; ++kt) {
    __syncthreads();
#pragma unroll
    for (int p = 0; p < 2; ++p) {
      int cc = p * 256 + t;
      int row = cc >> 3, c8 = (cc & 7) * 8;
      uint4 kv = *(const uint4*)(qkv + (size_t)(kt * 64 + row) * 3072 + 1024 + h * 64 + c8);
      *(uint4*)((char*)Ks + swz128(row, c8 * 2)) = kv;
      uint4 vv = *(const uint4*)(vt + (size_t)(h * 64 + row) * 2048 + kt * 64 + c8);
      *(uint4*)((char*)Vs + swz128(row, c8 * 2)) = vv;
    }
    __syncthreads();

    // S^T[kv][q]: A = K (rows kv), B = Q (cols q); kvb = kv 32-block, chained over 2 ch halves
    f32x16 s0 = zero16(), s1 = zero16();
    {
      const int cb0 = (sub * 32 + g1 * 8) * 2;
      bf16x8 ka = __builtin_bit_cast(bf16x8, *(const uint4*)((const char*)Ks + swz128(ql, cb0)));
      bf16x8 kb = __builtin_bit_cast(bf16x8, *(const uint4*)((const char*)Ks + swz128(32 + ql, cb0)));
      s0 = __builtin_amdgcn_mfma_f32_32x32x16_bf16(ka, qf0, s0, 0, 0, 0);
      s1 = __builtin_amdgcn_mfma_f32_32x32x16_bf16(kb, qf0, s1, 0, 0, 0);
      const int cb1 = (sub * 32 + 16 + g1 * 8) * 2;
      bf16x8 kc = __builtin_bit_cast(bf16x8, *(const uint4*)((const char*)Ks + swz128(ql, cb1)));
      bf16x8 kd = __builtin_bit_cast(bf16x8, *(const uint4*)((const char*)Ks + swz128(32 + ql, cb1)));
      s0 = __builtin_amdgcn_mfma_f32_32x32x16_bf16(kc, qf1, s0, 0, 0, 0);
      s1 = __builtin_amdgcn_mfma_f32_32x32x16_bf16(kd, qf1, s1, 0, 0, 0);
    }

    // causal mask (raw S units); kv_local = (rg&3) + 4*g1 + 8*(rg>>2) + 32*kvb
    if (kt == qt) {
      const int lim = qh * 32 + ql;
#pragma unroll
      for (int rg = 0; rg < 16; ++rg) {
        int kv0 = (rg & 3) + 4 * g1 + 8 * (rg >> 2);
        if (kv0 > lim) s0[rg] = -1e30f;
        if (kv0 + 32 > lim) s1[rg] = -1e30f;
      }
    }

    // row max: 31 in-lane + 1 shfl (partner holds complementary kv of same q)
    float rm = fmaxf(s0[0], s1[0]);
#pragma unroll
    for (int rg = 1; rg < 16; ++rg) rm = fmaxf(rm, fmaxf(s0[rg], s1[rg]));
    rm = fmaxf(rm, __shfl_xor(rm, 32));

    float mn = fmaxf(mm, rm);
    float es = exp2f((mm - mn) * C1EXP);
    mm = mn;
    const float mnC = mn * C1EXP;
    float ps = 0.f;
#pragma unroll
    for (int rg = 0; rg < 16; ++rg) {
      float p0 = exp2f(__builtin_fmaf(s0[rg], C1EXP, -mnC));
      float p1 = exp2f(__builtin_fmaf(s1[rg], C1EXP, -mnC));
      s0[rg] = p0; s1[rg] = p1;
      ps += p0 + p1;
    }
    ps += __shfl_xor(ps, 32);
    lsum = lsum * es + ps;
    O0 *= es;
    O1 *= es;

    // pack P -> bf16 pairs: pk[kvb][q2][t] covers kv = 32kvb + 8q2 + 4g1 + 2t + {0,1}
    unsigned pk[2][4][2];
#pragma unroll
    for (int q2 = 0; q2 < 4; ++q2) {
      float a0 = s0[4 * q2 + 0], a1 = s0[4 * q2 + 1], a2 = s0[4 * q2 + 2], a3 = s0[4 * q2 + 3];
      float b0 = s1[4 * q2 + 0], b1 = s1[4 * q2 + 1], b2 = s1[4 * q2 + 2], b3 = s1[4 * q2 + 3];
      asm("v_cvt_pk_bf16_f32 %0, %1, %2" : "=v"(pk[0][q2][0]) : "v"(a0), "v"(a1));
      asm("v_cvt_pk_bf16_f32 %0, %1, %2" : "=v"(pk[0][q2][1]) : "v"(a2), "v"(a3));
      asm("v_cvt_pk_bf16_f32 %0, %1, %2" : "=v"(pk[1][q2][0]) : "v"(b0), "v"(b1));
      asm("v_cvt_pk_bf16_f32 %0, %1, %2" : "=v"(pk[1][q2][1]) : "v"(b2), "v"(b3));
    }
    // redistribute to B-operand layout: swap(D,S): D'={D.lo,S.lo}, S'={D.hi,S.hi}
#pragma unroll
    for (int kvb = 0; kvb < 2; ++kvb) {
      asm volatile("v_permlane32_swap_b32 %0, %1" : "+v"(pk[kvb][0][0]), "+v"(pk[kvb][1][0]));
      asm volatile("v_permlane32_swap_b32 %0, %1" : "+v"(pk[kvb][0][1]), "+v"(pk[kvb][1][1]));
      asm volatile("v_permlane32_swap_b32 %0, %1" : "+v"(pk[kvb][2][0]), "+v"(pk[kvb][3][0]));
      asm volatile("v_permlane32_swap_b32 %0, %1" : "+v"(pk[kvb][2][1]), "+v"(pk[kvb][3][1]));
    }

    // PV: O^T[d][q] += V^T[d][kv] . P[kv][q]; ks covers kv 16-block
#pragma unroll
    for (int ks = 0; ks < 4; ++ks) {
      const int kvb = ks >> 1, kshi = ks & 1;
      uint4 pu;
      pu.x = pk[kvb][2 * kshi][0];
      pu.y = pk[kvb][2 * kshi][1];
      pu.z = pk[kvb][2 * kshi + 1][0];
      pu.w = pk[kvb][2 * kshi + 1][1];
      bf16x8 pf = __builtin_bit_cast(bf16x8, pu);
      const int cb = (ks * 16 + g1 * 8) * 2;
      bf16x8 v0 = __builtin_bit_cast(bf16x8, *(const uint4*)((const char*)Vs + swz128(ql, cb)));
      bf16x8 v1 = __builtin_bit_cast(bf16x8, *(const uint4*)((const char*)Vs + swz128(32 + ql, cb)));
      O0 = __builtin_amdgcn_mfma_f32_32x32x16_bf16(v0, pf, O0, 0, 0, 0);
      O1 = __builtin_amdgcn_mfma_f32_32x32x16_bf16(v1, pf, O1, 0, 0, 0);
    }
  }

  // write partials: pML fp32, pO fp16. O^T: d = dblk*32 + (rg&3) + 4g1 + 8(rg>>2), q = ql.
  const int qrow = qh * 32 + ql;
  float* pml = pML + (size_t)pid * 256 + sub * 128;
  if (g1 == 0) {
    pml[qrow] = mm;
    pml[64 + qrow] = lsum;
  }
  ushort* po = pOh + ((size_t)(pid * 2 + sub) * 64 + qrow) * 64;
#pragma unroll
  for (int q2 = 0; q2 < 4; ++q2) {
    uint2 u0, u1;
    u0.x = (unsigned)f2h(O0[4 * q2 + 0]) | ((unsigned)f2h(O0[4 * q2 + 1]) << 16);
    u0.y = (unsigned)f2h(O0[4 * q2 + 2]) | ((unsigned)f2h(O0[4 * q2 + 3]) << 16);
    u1.x = (unsigned)f2h(O1[4 * q2 + 0]) | ((unsigned)f2h(O1[4 * q2 + 1]) << 16);
    u1.y = (unsigned)f2h(O1[4 * q2 + 2]) | ((unsigned)f2h(O1[4 * q2 + 3]) << 16);
    *(uint2*)(po + q2 * 8 + g1 * 4) = u0;
    *(uint2*)(po + 32 + q2 * 8 + g1 * 4) = u1;
  }
}

// ---------------- combine partials + diff + RMSNorm ----------------
// block = (qt, h), 256 threads: thread t -> row = t>>2, quad = t&3 (16 ch each)
__global__ __launch_bounds__(256) void combine_kernel(
    const ushort* __restrict__ pOh, const float* __restrict__ pML,
    const float* __restrict__ lq1, const float* __restrict__ lk1,
    const float* __restrict__ lq2, const float* __restrict__ lk2,
    const float* __restrict__ gamma, ushort* __restrict__ attn_out) {
  const int qt = blockIdx.x, h = blockIdx.y;
  const int nc = (qt >> 2) + 1;
  const int pbase = h * 144 + qoff4(qt);
  const int t = threadIdx.x, row = t >> 2, quad = t & 3;
  const int lane = t & 63;

  // lambda = exp(lq1.lk1) - exp(lq2.lk2) + LAM_INIT
  float lam;
  {
    int d = lane & 31;
    float a1 = lq1[d] * lk1[d];
    float a2 = lq2[d] * lk2[d];
#pragma unroll
    for (int m = 16; m >= 1; m >>= 1) {
      a1 += __shfl_xor(a1, m);
      a2 += __shfl_xor(a2, m);
    }
    lam = expf(a1) - expf(a2) + LAM_INIT;
  }

  float M[2] = {-1e30f, -1e30f};
  for (int c = 0; c < nc; ++c) {
    const float* ml = pML + (size_t)(pbase + c) * 256;
    M[0] = fmaxf(M[0], ml[row]);
    M[1] = fmaxf(M[1], ml[128 + row]);
  }
  float L[2] = {0.f, 0.f};
  float acc[2][16];
#pragma unroll
  for (int s = 0; s < 2; ++s)
#pragma unroll
    for (int v = 0; v < 16; ++v) acc[s][v] = 0.f;

  for (int c = 0; c < nc; ++c) {
    const int pid = pbase + c;
    const float* ml = pML + (size_t)pid * 256;
#pragma unroll
    for (int s = 0; s < 2; ++s) {
      float mc = ml[s * 128 + row];
      float lc = ml[s * 128 + 64 + row];
      float wgt = exp2f((mc - M[s]) * C1EXP);  // raw-S units
      L[s] += lc * wgt;
      const ushort* op = pOh + ((size_t)(pid * 2 + s) * 64 + row) * 64 + quad * 16;
      uint4 ua = *(const uint4*)op;
      uint4 ub = *(const uint4*)(op + 8);
      unsigned uu[8] = {ua.x, ua.y, ua.z, ua.w, ub.x, ub.y, ub.z, ub.w};
#pragma unroll
      for (int j = 0; j < 8; ++j) {
        acc[s][2 * j + 0] += h2f((ushort)(uu[j] & 0xffffu)) * wgt;
        acc[s][2 * j + 1] += h2f((ushort)(uu[j] >> 16)) * wgt;
      }
    }
  }

  float inv0 = 1.f / L[0], inv1 = 1.f / L[1];
  float wv[16], ss = 0.f;
#pragma unroll
  for (int j = 0; j < 16; ++j) {
    float val = acc[0][j] * inv0 - lam * (acc[1][j] * inv1);
    wv[j] = val;
    ss += val * val;
  }
  ss += __shfl_xor(ss, 1);
  ss += __shfl_xor(ss, 2);
  float scl = rsqrtf(ss * (1.f / 64.f) + 1e-5f) * ONE_M_LI;

  union { ushort hs[16]; uint4 u[2]; } outp;
#pragma unroll
  for (int j = 0; j < 16; ++j)
    outp.hs[j] = f2b(wv[j] * scl * gamma[quad * 16 + j]);
  uint4* dst = (uint4*)(attn_out + (size_t)(qt * 64 + row) * 1024 + h * 64 + quad * 16);
  dst[0] = outp.u[0];
  dst[1] = outp.u[1];
}

// ---------------- fallback: single-pass fused attention (R1 version) ----------------
__global__ __launch_bounds__(256) void attn_kernel(
    const ushort* __restrict__ qkv, const ushort* __restrict__ vt,
    const float* __restrict__ lq1, const float* __restrict__ lk1,
    const float* __restrict__ lq2, const float* __restrict__ lk2,
    const float* __restrict__ gamma, ushort* __restrict__ attn_out) {
  __shared__ __align__(16) ushort Ks[64 * 64];
  __shared__ __align__(16) ushort Vs[64 * 64];
  __shared__ __align__(16) ushort Ps[4 * 2 * 1024];

  const int qt = blockIdx.x, h = blockIdx.y;
  const int t = threadIdx.x, lane = t & 63, w = t >> 6;
  const int g = lane >> 4, r = lane & 15;

  float lam;
  {
    int d = lane & 31;
    float a1 = lq1[d] * lk1[d];
    float a2 = lq2[d] * lk2[d];
#pragma unroll
    for (int m = 16; m >= 1; m >>= 1) {
      a1 += __shfl_xor(a1, m);
      a2 += __shfl_xor(a2, m);
    }
    lam = expf(a1) - expf(a2) + LAM_INIT;
  }

  const int qrow0 = qt * 64 + w * 16;
  bf16x8 q1f = __builtin_bit_cast(bf16x8, *(const uint4*)(qkv + (size_t)(qrow0 + r) * 3072 + h * 64 + g * 8));
  bf16x8 q2f = __builtin_bit_cast(bf16x8, *(const uint4*)(qkv + (size_t)(qrow0 + r) * 3072 + h * 64 + 32 + g * 8));

  f32x4 O[2][4];
  float mm[2][4], ll[2][4];
#pragma unroll
  for (int sub = 0; sub < 2; ++sub)
#pragma unroll
    for (int e = 0; e < 4; ++e) {
      mm[sub][e] = -1e30f;
      ll[sub][e] = 0.f;
      O[sub][e] = (f32x4){0.f, 0.f, 0.f, 0.f};
    }

  for (int kt = 0; kt <= qt; ++kt) {
    __syncthreads();
#pragma unroll
    for (int p = 0; p < 2; ++p) {
      int cc = p * 256 + t;
      int row = cc >> 3, c8 = (cc & 7) * 8;
      uint4 kv = *(const uint4*)(qkv + (size_t)(kt * 64 + row) * 3072 + 1024 + h * 64 + c8);
      *(uint4*)((char*)Ks + swz128(row, c8 * 2)) = kv;
      uint4 vv = *(const uint4*)(vt + (size_t)(h * 64 + row) * 2048 + kt * 64 + c8);
      *(uint4*)((char*)Vs + swz128(row, c8 * 2)) = vv;
    }
    __syncthreads();

    f32x4 sv[2][4];
    const f32x4 zz = {0.f, 0.f, 0.f, 0.f};
#pragma unroll
    for (int f = 0; f < 4; ++f) {
      int krow = f * 16 + r;
      bf16x8 k1f = __builtin_bit_cast(bf16x8, *(const uint4*)((const char*)Ks + swz128(krow, g * 16)));
      bf16x8 k2f = __builtin_bit_cast(bf16x8, *(const uint4*)((const char*)Ks + swz128(krow, 64 + g * 16)));
      sv[0][f] = __builtin_amdgcn_mfma_f32_16x16x32_bf16(q1f, k1f, zz, 0, 0, 0);
      sv[1][f] = __builtin_amdgcn_mfma_f32_16x16x32_bf16(q2f, k2f, zz, 0, 0, 0);
    }

    const bool diag = (kt == qt);
#pragma unroll
    for (int sub = 0; sub < 2; ++sub) {
      float rmax[4];
#pragma unroll
      for (int e = 0; e < 4; ++e) {
        float mx = -1e30f;
#pragma unroll
        for (int f = 0; f < 4; ++f) {
          float v = sv[sub][f][e] * SCALE;
          if (diag && (f * 16 + r) > (w * 16 + g * 4 + e)) v = -1e30f;
          sv[sub][f][e] = v;
          mx = fmaxf(mx, v);
        }
        rmax[e] = mx;
      }
#pragma unroll
      for (int d = 1; d <= 8; d <<= 1)
#pragma unroll
        for (int e = 0; e < 4; ++e) rmax[e] = fmaxf(rmax[e], __shfl_xor(rmax[e], d));
#pragma unroll
      for (int e = 0; e < 4; ++e) {
        float mn = fmaxf(mm[sub][e], rmax[e]);
        float es = exp2f((mm[sub][e] - mn) * LOG2E);
        mm[sub][e] = mn;
        float psum = 0.f;
#pragma unroll
        for (int f = 0; f < 4; ++f) {
          float p = exp2f((sv[sub][f][e] - mn) * LOG2E);
          sv[sub][f][e] = p;
          psum += p;
        }
#pragma unroll
        for (int d = 1; d <= 8; d <<= 1) psum += __shfl_xor(psum, d);
        ll[sub][e] = ll[sub][e] * es + psum;
#pragma unroll
        for (int cf = 0; cf < 4; ++cf) O[sub][cf][e] *= es;
      }
      char* pb = (char*)Ps + (size_t)(w * 2 + sub) * 2048;
#pragma unroll
      for (int f = 0; f < 4; ++f)
#pragma unroll
        for (int e = 0; e < 4; ++e) {
          int prow = g * 4 + e, pcol = f * 16 + r;
          *(ushort*)(pb + swz128(prow, pcol * 2)) = f2b(sv[sub][f][e]);
        }
    }

    char* pb0 = (char*)Ps + (size_t)(w * 2 + 0) * 2048;
    char* pb1 = (char*)Ps + (size_t)(w * 2 + 1) * 2048;
#pragma unroll
    for (int ks = 0; ks < 2; ++ks) {
      int cb = (ks * 32 + g * 8) * 2;
      bf16x8 pa0 = __builtin_bit_cast(bf16x8, *(const uint4*)(pb0 + swz128(r, cb)));
      bf16x8 pa1 = __builtin_bit_cast(bf16x8, *(const uint4*)(pb1 + swz128(r, cb)));
#pragma unroll
      for (int cf = 0; cf < 4; ++cf) {
        int vrow = cf * 16 + r;
        bf16x8 vf = __builtin_bit_cast(bf16x8, *(const uint4*)((const char*)Vs + swz128(vrow, cb)));
        O[0][cf] = __builtin_amdgcn_mfma_f32_16x16x32_bf16(pa0, vf, O[0][cf], 0, 0, 0);
        O[1][cf] = __builtin_amdgcn_mfma_f32_16x16x32_bf16(pa1, vf, O[1][cf], 0, 0, 0);
      }
    }
  }

  float inv0[4], inv1[4];
#pragma unroll
  for (int e = 0; e < 4; ++e) {
    inv0[e] = 1.f / ll[0][e];
    inv1[e] = 1.f / ll[1][e];
  }
  float wv[4][4], ss[4] = {0.f, 0.f, 0.f, 0.f};
#pragma unroll
  for (int cf = 0; cf < 4; ++cf)
#pragma unroll
    for (int e = 0; e < 4; ++e) {
      float v = O[0][cf][e] * inv0[e] - lam * (O[1][cf][e] * inv1[e]);
      wv[cf][e] = v;
      ss[e] += v * v;
    }
#pragma unroll
  for (int d = 1; d <= 8; d <<= 1)
#pragma unroll
    for (int e = 0; e < 4; ++e) ss[e] += __shfl_xor(ss[e], d);
  float scl[4];
#pragma unroll
  for (int e = 0; e < 4; ++e) scl[e] = rsqrtf(ss[e] * (1.f / 64.f) + 1e-5f) * ONE_M_LI;
#pragma unroll
  for (int cf = 0; cf < 4; ++cf) {
    float gv = gamma[cf * 16 + r];
#pragma unroll
    for (int e = 0; e < 4; ++e) {
      float v = wv[cf][e] * scl[e] * gv;
      attn_out[(size_t)(qrow0 + g * 4 + e) * 1024 + h * 64 + cf * 16 + r] = f2b(v);
    }
  }
}

extern "C" void kernel_launch(void* const* d_in, const int* in_sizes, int n_in,
                              void* d_out, int out_size, void* d_ws, size_t ws_size,
                              hipStream_t stream) {
  const float* x = (const float*)d_in[0];
  const float* Wq = (const float*)d_in[1];
  const float* Wk = (const float*)d_in[2];
  const float* Wv = (const float*)d_in[3];
  const float* Wo = (const float*)d_in[4];
  const float* lq1 = (const float*)d_in[5];
  const float* lk1 = (const float*)d_in[6];
  const float* lq2 = (const float*)d_in[7];
  const float* lk2 = (const float*)d_in[8];
  const float* gamma = (const float*)d_in[9];
  (void)in_sizes; (void)n_in; (void)out_size;

  char* ws = (char*)d_ws;
  ushort* xb = (ushort*)(ws);
  ushort* w1 = (ushort*)(ws + (4ull << 20));
  ushort* wob = (ushort*)(ws + (10ull << 20));
  ushort* qkv = (ushort*)(ws + (12ull << 20));
  ushort* vt = (ushort*)(ws + (24ull << 20));
  ushort* atn = (ushort*)(ws + (28ull << 20));
  float* cosT = (float*)(ws + (32ull << 20));
  float* sinT = (float*)(ws + (32ull << 20) + 2048 * 16 * 4);
  const size_t pO_off = (33ull << 20);
  const size_t pml_off = pO_off + 2304ull * 2 * 64 * 64 * 2;  // fp16 partials
  ushort* pOh = (ushort*)(ws + pO_off);
  float* pML = (float*)(ws + pml_off);
  const size_t ws_needed = pml_off + 2304ull * 256 * 4;

  prep_kernel<<<24704, 256, 0, stream>>>(x, Wq, Wk, Wv, Wo, xb, w1, wob, cosT, sinT);
  gemm_bt<<<dim3(24, 16), 256, 0, stream>>>(xb, w1, (void*)qkv, 2048, 3072, 1024, 1);
  rope_kernel<<<8192, 256, 0, stream>>>(qkv, cosT, sinT);
  transv_kernel<<<dim3(16, 32), 256, 0, stream>>>(qkv, vt);
  if (ws_size >= ws_needed) {
    attn_split_kernel<<<dim3(144, 16), 256, 0, stream>>>(qkv, vt, pOh, pML);
    combine_kernel<<<dim3(32, 16), 256, 0, stream>>>(pOh, pML, lq1, lk1, lq2, lk2, gamma, atn);
  } else {
    attn_kernel<<<dim3(32, 16), 256, 0, stream>>>(qkv, vt, lq1, lk1, lq2, lk2, gamma, atn);
  }
  gemm_bt<<<dim3(8, 16), 256, 0, stream>>>(atn, wob, d_out, 2048, 1024, 1024, 0);
}

// Round 4
// 124.365 us; speedup vs baseline: 1.7200x; 1.0673x over previous
//
#include <hip/hip_runtime.h>
#include <hip/hip_bf16.h>
#include <math.h>

// Differential attention, bf16 MFMA pipeline, split-KV flash attention with
// swapped-operand 32x32x16 MFMA softmax (T12 structure). R4: m97-style
// global_load_lds staging in GEMM + attn (pre-swizzled global source).
// ws layout (bytes):
//   [0,4M)    xb      x as bf16             2048x1024
//   [4M,10M)  w1      [Wq;Wk;Wv] bf16       3072x1024
//   [10M,12M) wob     Wo bf16               1024x1024
//   [12M,24M) qkv     bf16, row stride 3072 (q|k|v); rope applied in-place to q,k
//   [24M,28M) vt      v transposed bf16     1024x2048  vt[d][s]
//   [28M,32M) atn     normalized wv bf16    2048x1024
//   [32M,+256K) cos/sin tables fp32         2048x16 each
//   [33M,+37.75M)  pOh  fp16 partial O  [2304 pids][2 subs][64 q][64 d]
//   [33M+37.75M,+2.36M) pML fp32 partial m,l [2304][2][2][64]
// pid = h*144 + qoff4(qt) + chunk;  chunk = 256 kv rows (4 k-tiles of 64)

typedef __bf16 bf16x8 __attribute__((ext_vector_type(8)));
typedef float f32x4 __attribute__((ext_vector_type(4)));
typedef float f32x16 __attribute__((ext_vector_type(16)));

#define LOG2E 1.4426950408889634f
#define SCALE 0.17677669529663687f /* 1/sqrt(32) */
#define C1EXP 0.25506100319239545f /* SCALE*LOG2E : exp2 scale for raw S */
#define LAM_INIT 0.783605766532f
#define ONE_M_LI 0.216394233468f

// async global->LDS, 16B per lane; lds base must be wave-uniform (lane scatters +l*16)
#define GLOAD16(g, l)                                                              \
  __builtin_amdgcn_global_load_lds((const __attribute__((address_space(1))) void*)(g), \
                                   (__attribute__((address_space(3))) void*)(l), 16, 0, 0)

__device__ __forceinline__ ushort f2b(float f) {
  unsigned u = __builtin_bit_cast(unsigned, f);
  u += 0x7fffu + ((u >> 16) & 1u);
  return (ushort)(u >> 16);
}
__device__ __forceinline__ float b2f(ushort h) {
  return __builtin_bit_cast(float, ((unsigned)h) << 16);
}
__device__ __forceinline__ ushort f2h(float f) {
  _Float16 h = (_Float16)f;
  return __builtin_bit_cast(ushort, h);
}
__device__ __forceinline__ float h2f(ushort u) {
  return (float)__builtin_bit_cast(_Float16, u);
}
// byte offset into a [rows][128B] LDS tile, XOR-swizzled (G4)
__device__ __forceinline__ int swz128(int row, int byteoff) {
  return row * 128 + (byteoff ^ ((row & 7) << 4));
}
// chunk=4 tiles: qoff4(qt) = sum_{q<qt} ceil((q+1)/4)
__device__ __forceinline__ int qoff4(int qt) {
  int G = qt >> 2, rem = qt & 3;
  return 2 * G * (G + 1) + rem * (G + 1);
}
__device__ __forceinline__ f32x16 zero16() {
  f32x16 z;
#pragma unroll
  for (int i = 0; i < 16; ++i) z[i] = 0.f;
  return z;
}

// ---------------- prep: converts (8 elems/thread) + rope tables ----------------
__global__ __launch_bounds__(256) void prep_kernel(
    const float* __restrict__ x, const float* __restrict__ Wq,
    const float* __restrict__ Wk, const float* __restrict__ Wv,
    const float* __restrict__ Wo,
    ushort* __restrict__ xb, ushort* __restrict__ w1, ushort* __restrict__ wob,
    float* __restrict__ cosT, float* __restrict__ sinT) {
  unsigned b = blockIdx.x;
  if (b < 3072u) {
    unsigned i8 = (b * 256u + threadIdx.x) * 8u;
    const float* s;
    ushort* d;
    if (i8 < 2097152u) { s = x + i8; d = xb + i8; }
    else if (i8 < 3145728u) { s = Wq + (i8 - 2097152u); d = w1 + (i8 - 2097152u); }
    else if (i8 < 4194304u) { s = Wk + (i8 - 3145728u); d = w1 + (i8 - 2097152u); }
    else if (i8 < 5242880u) { s = Wv + (i8 - 4194304u); d = w1 + (i8 - 2097152u); }
    else { s = Wo + (i8 - 5242880u); d = wob + (i8 - 5242880u); }
    float4 v0 = *(const float4*)s;
    float4 v1 = *(const float4*)(s + 4);
    union { ushort h[8]; uint4 u; } o;
    o.h[0] = f2b(v0.x); o.h[1] = f2b(v0.y); o.h[2] = f2b(v0.z); o.h[3] = f2b(v0.w);
    o.h[4] = f2b(v1.x); o.h[5] = f2b(v1.y); o.h[6] = f2b(v1.z); o.h[7] = f2b(v1.w);
    *(uint4*)d = o.u;
    return;
  }
  unsigned j = (b - 3072u) * 256u + threadIdx.x;  // 0..32767 : 2048 pos x 16 freqs
  int tt = (int)(j >> 4), jj = (int)(j & 15u);
  float inv = powf(10000.0f, -(float)(2 * jj) * (1.0f / 32.0f));
  float ang = (float)tt * inv;
  cosT[j] = cosf(ang);
  sinT[j] = sinf(ang);
}

// ---------------- rope (in-place on q,k halves of qkv) ----------------
__global__ void rope_kernel(ushort* __restrict__ qkv, const float* __restrict__ cosT,
                            const float* __restrict__ sinT) {
  unsigned i = blockIdx.x * 256u + threadIdx.x;  // 2M pairs
  int row = (int)(i >> 10), u = (int)(i & 1023u);
  int col = (u < 512) ? (2 * u) : (1024 + 2 * (u - 512));
  int j = u & 15;
  float c = cosT[row * 16 + j], s = sinT[row * 16 + j];
  unsigned v = *(const unsigned*)(qkv + (size_t)row * 3072 + col);
  float x1 = b2f((ushort)(v & 0xffffu));
  float x2 = b2f((ushort)(v >> 16));
  float ye = x1 * c - x2 * s;
  float yo = x1 * s + x2 * c;
  unsigned o = (unsigned)f2b(ye) | ((unsigned)f2b(yo) << 16);
  *(unsigned*)(qkv + (size_t)row * 3072 + col) = o;
}

// ---------------- transpose v -> vt[d][s] ----------------
__global__ __launch_bounds__(256) void transv_kernel(const ushort* __restrict__ qkv,
                                                     ushort* __restrict__ vt) {
  __shared__ __align__(16) ushort tile[64][80];
  const int t = threadIdx.x;
  const int d0 = blockIdx.x * 64, s0 = blockIdx.y * 64;
#pragma unroll
  for (int p = 0; p < 2; ++p) {
    int sl = p * 32 + (t >> 3), d8 = (t & 7) * 8;
    uint4 v = *(const uint4*)(qkv + (size_t)(s0 + sl) * 3072 + 2048 + d0 + d8);
    *(uint4*)(&tile[sl][d8]) = v;
  }
  __syncthreads();
#pragma unroll
  for (int p = 0; p < 2; ++p) {
    int dl = p * 32 + (t >> 3), s8 = (t & 7) * 8;
    union { ushort h[8]; uint4 u; } tmp;
#pragma unroll
    for (int jj = 0; jj < 8; ++jj) tmp.h[jj] = tile[s8 + jj][dl];
    *(uint4*)(vt + (size_t)(d0 + dl) * 2048 + s0 + s8) = tmp.u;
  }
}

// ---------------- GEMM: C[M,N] = A[M,K] . B[N,K]^T (m97: global_load_lds) --------
__global__ __launch_bounds__(256) void gemm_bt(const ushort* __restrict__ A,
                                               const ushort* __restrict__ B,
                                               void* __restrict__ C, int M, int N, int K,
                                               int out_bf16) {
  __shared__ __align__(16) ushort As[128 * 32];  // BK=32, linear (m97)
  __shared__ __align__(16) ushort Bs[128 * 32];
  const int t = threadIdx.x, lane = t & 63, w = t >> 6;
  const int g = lane >> 4, r = lane & 15;
  const int wr = w >> 1, wc = w & 1;
  const int m0 = blockIdx.y * 128, n0 = blockIdx.x * 128;

  f32x4 acc[4][4];
#pragma unroll
  for (int i = 0; i < 4; ++i)
#pragma unroll
    for (int j = 0; j < 4; ++j) acc[i][j] = (f32x4){0.f, 0.f, 0.f, 0.f};

  for (int k0 = 0; k0 < K; k0 += 32) {
    __syncthreads();  // previous iter's ds_reads done before overwrite
#pragma unroll
    for (int p = 0; p < 2; ++p) {
      int idx = (p * 4 + w) * 64 + lane;          // 16B-chunk id in tile
      int row = idx >> 2, ko = (idx & 3) * 8;     // 4 chunks of 8 elems per row
      const ushort* ga = A + (size_t)(m0 + row) * K + k0 + ko;
      const ushort* gb = B + (size_t)(n0 + row) * K + k0 + ko;
      GLOAD16(ga, As + (p * 4 + w) * 512);
      GLOAD16(gb, Bs + (p * 4 + w) * 512);
    }
    __syncthreads();  // drains vmcnt -> staged data visible
    bf16x8 af[4], bfr[4];
#pragma unroll
    for (int i = 0; i < 4; ++i) {
      af[i] = __builtin_bit_cast(bf16x8, *(const uint4*)(As + (wr * 64 + i * 16 + r) * 32 + g * 8));
      bfr[i] = __builtin_bit_cast(bf16x8, *(const uint4*)(Bs + (wc * 64 + i * 16 + r) * 32 + g * 8));
    }
#pragma unroll
    for (int mi = 0; mi < 4; ++mi)
#pragma unroll
      for (int ni = 0; ni < 4; ++ni)
        acc[mi][ni] = __builtin_amdgcn_mfma_f32_16x16x32_bf16(af[mi], bfr[ni], acc[mi][ni], 0, 0, 0);
  }
#pragma unroll
  for (int mi = 0; mi < 4; ++mi)
#pragma unroll
    for (int ni = 0; ni < 4; ++ni)
#pragma unroll
      for (int e = 0; e < 4; ++e) {
        int row = m0 + wr * 64 + mi * 16 + g * 4 + e;
        int col = n0 + wc * 64 + ni * 16 + r;
        float v = acc[mi][ni][e];
        if (out_bf16) ((ushort*)C)[(size_t)row * N + col] = f2b(v);
        else ((float*)C)[(size_t)row * N + col] = v;
      }
}

// ---------------- split-KV flash attention: 32x32 swapped-operand partials ----------------
// block = (work->(qt, chunk), head). 4 waves: wave w: sub = w&1, qhalf = w>>1.
// S^T = mfma(K, Q): lane holds P-column for its q-row -> in-lane softmax.
// P packed to bf16 in-register (cvt_pk + permlane32_swap), O^T = mfma(V^T, P).
// K/V staged via global_load_lds with PRE-SWIZZLED global source (rule #21):
// linear LDS dest + source col ^= ((row&7)<<4) + swizzled read = consistent.
__global__ __launch_bounds__(256, 3) void attn_split_kernel(
    const ushort* __restrict__ qkv, const ushort* __restrict__ vt,
    ushort* __restrict__ pOh, float* __restrict__ pML) {
  __shared__ __align__(16) ushort Ks[64 * 64];  // [kv row][64ch k1|k2], swizzled content
  __shared__ __align__(16) ushort Vs[64 * 64];  // vt tile [d][kv], swizzled content

  // decode blockIdx.x in [0,144) -> (qt, c)
  int wi = blockIdx.x, qt = 0, c = 0;
  for (int q = 0; q < 32; ++q) {
    int nc = (q >> 2) + 1;
    if (wi < nc) { qt = q; c = wi; break; }
    wi -= nc;
  }
  const int h = blockIdx.y;
  const int pid = h * 144 + qoff4(qt) + c;
  const int t = threadIdx.x, lane = t & 63, w = t >> 6;
  const int sub = w & 1, qh = w >> 1;
  const int ql = lane & 31, g1 = lane >> 5;
  const int qa = qt * 64 + qh * 32 + ql;  // absolute q row for this lane

  // Q as B-operand: B[q=lane&31][ch = chain*16 + g1*8 + j]
  bf16x8 qf0 = __builtin_bit_cast(bf16x8, *(const uint4*)(qkv + (size_t)qa * 3072 + h * 64 + sub * 32 + g1 * 8));
  bf16x8 qf1 = __builtin_bit_cast(bf16x8, *(const uint4*)(qkv + (size_t)qa * 3072 + h * 64 + sub * 32 + 16 + g1 * 8));

  f32x16 O0 = zero16(), O1 = zero16();  // O^T[d][q = lane&31]
  float mm = -1e30f, lsum = 0.f;

  const int ktb = c * 4;
  const int kte = min(ktb + 4, qt + 1);
  for (int kt = ktb; kt < kte; ++kt) {
    __syncthreads();
#pragma unroll
    for (int p = 0; p < 2; ++p) {
      int idx = (p * 4 + w) * 64 + lane;                       // 16B-chunk id
      int row = idx >> 3;                                      // 8 chunks per 128B row
      int kbs = ((idx & 7) * 16) ^ ((row & 7) << 4);           // pre-swizzled col byte
      const ushort* gk = qkv + (size_t)(kt * 64 + row) * 3072 + 1024 + h * 64 + (kbs >> 1);
      const ushort* gv = vt + (size_t)(h * 64 + row) * 2048 + kt * 64 + (kbs >> 1);
      GLOAD16(gk, Ks + (p * 4 + w) * 512);
      GLOAD16(gv, Vs + (p * 4 + w) * 512);
    }
    __syncthreads();

    // S^T[kv][q]: A = K (rows kv), B = Q (cols q)
    f32x16 s0 = zero16(), s1 = zero16();
    {
      const int cb0 = (sub * 32 + g1 * 8) * 2;
      bf16x8 ka = __builtin_bit_cast(bf16x8, *(const uint4*)((const char*)Ks + swz128(ql, cb0)));
      bf16x8 kb = __builtin_bit_cast(bf16x8, *(const uint4*)((const char*)Ks + swz128(32 + ql, cb0)));
      s0 = __builtin_amdgcn_mfma_f32_32x32x16_bf16(ka, qf0, s0, 0, 0, 0);
      s1 = __builtin_amdgcn_mfma_f32_32x32x16_bf16(kb, qf0, s1, 0, 0, 0);
      const int cb1 = (sub * 32 + 16 + g1 * 8) * 2;
      bf16x8 kc = __builtin_bit_cast(bf16x8, *(const uint4*)((const char*)Ks + swz128(ql, cb1)));
      bf16x8 kd = __builtin_bit_cast(bf16x8, *(const uint4*)((const char*)Ks + swz128(32 + ql, cb1)));
      s0 = __builtin_amdgcn_mfma_f32_32x32x16_bf16(kc, qf1, s0, 0, 0, 0);
      s1 = __builtin_amdgcn_mfma_f32_32x32x16_bf16(kd, qf1, s1, 0, 0, 0);
    }

    // causal mask (raw S units); kv_local = (rg&3) + 4*g1 + 8*(rg>>2) + 32*kvb
    if (kt == qt) {
      const int lim = qh * 32 + ql;
#pragma unroll
      for (int rg = 0; rg < 16; ++rg) {
        int kv0 = (rg & 3) + 4 * g1 + 8 * (rg >> 2);
        if (kv0 > lim) s0[rg] = -1e30f;
        if (kv0 + 32 > lim) s1[rg] = -1e30f;
      }
    }

    // row max: 31 in-lane + 1 shfl (partner holds complementary kv of same q)
    float rm = fmaxf(s0[0], s1[0]);
#pragma unroll
    for (int rg = 1; rg < 16; ++rg) rm = fmaxf(rm, fmaxf(s0[rg], s1[rg]));
    rm = fmaxf(rm, __shfl_xor(rm, 32));

    float mn = fmaxf(mm, rm);
    float es = exp2f((mm - mn) * C1EXP);
    mm = mn;
    const float mnC = mn * C1EXP;
    float ps = 0.f;
#pragma unroll
    for (int rg = 0; rg < 16; ++rg) {
      float p0 = exp2f(__builtin_fmaf(s0[rg], C1EXP, -mnC));
      float p1 = exp2f(__builtin_fmaf(s1[rg], C1EXP, -mnC));
      s0[rg] = p0; s1[rg] = p1;
      ps += p0 + p1;
    }
    ps += __shfl_xor(ps, 32);
    lsum = lsum * es + ps;
    O0 *= es;
    O1 *= es;

    // pack P -> bf16 pairs: pk[kvb][q2][t] covers kv = 32kvb + 8q2 + 4g1 + 2t + {0,1}
    unsigned pk[2][4][2];
#pragma unroll
    for (int q2 = 0; q2 < 4; ++q2) {
      float a0 = s0[4 * q2 + 0], a1 = s0[4 * q2 + 1], a2 = s0[4 * q2 + 2], a3 = s0[4 * q2 + 3];
      float b0 = s1[4 * q2 + 0], b1 = s1[4 * q2 + 1], b2 = s1[4 * q2 + 2], b3 = s1[4 * q2 + 3];
      asm("v_cvt_pk_bf16_f32 %0, %1, %2" : "=v"(pk[0][q2][0]) : "v"(a0), "v"(a1));
      asm("v_cvt_pk_bf16_f32 %0, %1, %2" : "=v"(pk[0][q2][1]) : "v"(a2), "v"(a3));
      asm("v_cvt_pk_bf16_f32 %0, %1, %2" : "=v"(pk[1][q2][0]) : "v"(b0), "v"(b1));
      asm("v_cvt_pk_bf16_f32 %0, %1, %2" : "=v"(pk[1][q2][1]) : "v"(b2), "v"(b3));
    }
#pragma unroll
    for (int kvb = 0; kvb < 2; ++kvb) {
      asm volatile("v_permlane32_swap_b32 %0, %1" : "+v"(pk[kvb][0][0]), "+v"(pk[kvb][1][0]));
      asm volatile("v_permlane32_swap_b32 %0, %1" : "+v"(pk[kvb][0][1]), "+v"(pk[kvb][1][1]));
      asm volatile("v_permlane32_swap_b32 %0, %1" : "+v"(pk[kvb][2][0]), "+v"(pk[kvb][3][0]));
      asm volatile("v_permlane32_swap_b32 %0, %1" : "+v"(pk[kvb][2][1]), "+v"(pk[kvb][3][1]));
    }

    // PV: O^T[d][q] += V^T[d][kv] . P[kv][q]; ks covers kv 16-block
#pragma unroll
    for (int ks = 0; ks < 4; ++ks) {
      const int kvb = ks >> 1, kshi = ks & 1;
      uint4 pu;
      pu.x = pk[kvb][2 * kshi][0];
      pu.y = pk[kvb][2 * kshi][1];
      pu.z = pk[kvb][2 * kshi + 1][0];
      pu.w = pk[kvb][2 * kshi + 1][1];
      bf16x8 pf = __builtin_bit_cast(bf16x8, pu);
      const int cb = (ks * 16 + g1 * 8) * 2;
      bf16x8 v0 = __builtin_bit_cast(bf16x8, *(const uint4*)((const char*)Vs + swz128(ql, cb)));
      bf16x8 v1 = __builtin_bit_cast(bf16x8, *(const uint4*)((const char*)Vs + swz128(32 + ql, cb)));
      O0 = __builtin_amdgcn_mfma_f32_32x32x16_bf16(v0, pf, O0, 0, 0, 0);
      O1 = __builtin_amdgcn_mfma_f32_32x32x16_bf16(v1, pf, O1, 0, 0, 0);
    }
  }

  // write partials: pML fp32, pO fp16. O^T: d = dblk*32 + (rg&3) + 4g1 + 8(rg>>2), q = ql.
  const int qrow = qh * 32 + ql;
  float* pml = pML + (size_t)pid * 256 + sub * 128;
  if (g1 == 0) {
    pml[qrow] = mm;
    pml[64 + qrow] = lsum;
  }
  ushort* po = pOh + ((size_t)(pid * 2 + sub) * 64 + qrow) * 64;
#pragma unroll
  for (int q2 = 0; q2 < 4; ++q2) {
    uint2 u0, u1;
    u0.x = (unsigned)f2h(O0[4 * q2 + 0]) | ((unsigned)f2h(O0[4 * q2 + 1]) << 16);
    u0.y = (unsigned)f2h(O0[4 * q2 + 2]) | ((unsigned)f2h(O0[4 * q2 + 3]) << 16);
    u1.x = (unsigned)f2h(O1[4 * q2 + 0]) | ((unsigned)f2h(O1[4 * q2 + 1]) << 16);
    u1.y = (unsigned)f2h(O1[4 * q2 + 2]) | ((unsigned)f2h(O1[4 * q2 + 3]) << 16);
    *(uint2*)(po + q2 * 8 + g1 * 4) = u0;
    *(uint2*)(po + 32 + q2 * 8 + g1 * 4) = u1;
  }
}

// ---------------- combine partials + diff + RMSNorm ----------------
// block = (qt, h), 256 threads: thread t -> row = t>>2, quad = t&3 (16 ch each)
__global__ __launch_bounds__(256) void combine_kernel(
    const ushort* __restrict__ pOh, const float* __restrict__ pML,
    const float* __restrict__ lq1, const float* __restrict__ lk1,
    const float* __restrict__ lq2, const float* __restrict__ lk2,
    const float* __restrict__ gamma, ushort* __restrict__ attn_out) {
  const int qt = blockIdx.x, h = blockIdx.y;
  const int nc = (qt >> 2) + 1;
  const int pbase = h * 144 + qoff4(qt);
  const int t = threadIdx.x, row = t >> 2, quad = t & 3;
  const int lane = t & 63;

  // lambda = exp(lq1.lk1) - exp(lq2.lk2) + LAM_INIT
  float lam;
  {
    int d = lane & 31;
    float a1 = lq1[d] * lk1[d];
    float a2 = lq2[d] * lk2[d];
#pragma unroll
    for (int m = 16; m >= 1; m >>= 1) {
      a1 += __shfl_xor(a1, m);
      a2 += __shfl_xor(a2, m);
    }
    lam = expf(a1) - expf(a2) + LAM_INIT;
  }

  float M[2] = {-1e30f, -1e30f};
  for (int c = 0; c < nc; ++c) {
    const float* ml = pML + (size_t)(pbase + c) * 256;
    M[0] = fmaxf(M[0], ml[row]);
    M[1] = fmaxf(M[1], ml[128 + row]);
  }
  float L[2] = {0.f, 0.f};
  float acc[2][16];
#pragma unroll
  for (int s = 0; s < 2; ++s)
#pragma unroll
    for (int v = 0; v < 16; ++v) acc[s][v] = 0.f;

  for (int c = 0; c < nc; ++c) {
    const int pid = pbase + c;
    const float* ml = pML + (size_t)pid * 256;
#pragma unroll
    for (int s = 0; s < 2; ++s) {
      float mc = ml[s * 128 + row];
      float lc = ml[s * 128 + 64 + row];
      float wgt = exp2f((mc - M[s]) * C1EXP);  // raw-S units
      L[s] += lc * wgt;
      const ushort* op = pOh + ((size_t)(pid * 2 + s) * 64 + row) * 64 + quad * 16;
      uint4 ua = *(const uint4*)op;
      uint4 ub = *(const uint4*)(op + 8);
      unsigned uu[8] = {ua.x, ua.y, ua.z, ua.w, ub.x, ub.y, ub.z, ub.w};
#pragma unroll
      for (int j = 0; j < 8; ++j) {
        acc[s][2 * j + 0] += h2f((ushort)(uu[j] & 0xffffu)) * wgt;
        acc[s][2 * j + 1] += h2f((ushort)(uu[j] >> 16)) * wgt;
      }
    }
  }

  float inv0 = 1.f / L[0], inv1 = 1.f / L[1];
  float wv[16], ss = 0.f;
#pragma unroll
  for (int j = 0; j < 16; ++j) {
    float val = acc[0][j] * inv0 - lam * (acc[1][j] * inv1);
    wv[j] = val;
    ss += val * val;
  }
  ss += __shfl_xor(ss, 1);
  ss += __shfl_xor(ss, 2);
  float scl = rsqrtf(ss * (1.f / 64.f) + 1e-5f) * ONE_M_LI;

  union { ushort hs[16]; uint4 u[2]; } outp;
#pragma unroll
  for (int j = 0; j < 16; ++j)
    outp.hs[j] = f2b(wv[j] * scl * gamma[quad * 16 + j]);
  uint4* dst = (uint4*)(attn_out + (size_t)(qt * 64 + row) * 1024 + h * 64 + quad * 16);
  dst[0] = outp.u[0];
  dst[1] = outp.u[1];
}

extern "C" void kernel_launch(void* const* d_in, const int* in_sizes, int n_in,
                              void* d_out, int out_size, void* d_ws, size_t ws_size,
                              hipStream_t stream) {
  const float* x = (const float*)d_in[0];
  const float* Wq = (const float*)d_in[1];
  const float* Wk = (const float*)d_in[2];
  const float* Wv = (const float*)d_in[3];
  const float* Wo = (const float*)d_in[4];
  const float* lq1 = (const float*)d_in[5];
  const float* lk1 = (const float*)d_in[6];
  const float* lq2 = (const float*)d_in[7];
  const float* lk2 = (const float*)d_in[8];
  const float* gamma = (const float*)d_in[9];
  (void)in_sizes; (void)n_in; (void)out_size; (void)ws_size;

  char* ws = (char*)d_ws;
  ushort* xb = (ushort*)(ws);
  ushort* w1 = (ushort*)(ws + (4ull << 20));
  ushort* wob = (ushort*)(ws + (10ull << 20));
  ushort* qkv = (ushort*)(ws + (12ull << 20));
  ushort* vt = (ushort*)(ws + (24ull << 20));
  ushort* atn = (ushort*)(ws + (28ull << 20));
  float* cosT = (float*)(ws + (32ull << 20));
  float* sinT = (float*)(ws + (32ull << 20) + 2048 * 16 * 4);
  const size_t pO_off = (33ull << 20);
  const size_t pml_off = pO_off + 2304ull * 2 * 64 * 64 * 2;  // fp16 partials
  ushort* pOh = (ushort*)(ws + pO_off);
  float* pML = (float*)(ws + pml_off);

  prep_kernel<<<3200, 256, 0, stream>>>(x, Wq, Wk, Wv, Wo, xb, w1, wob, cosT, sinT);
  gemm_bt<<<dim3(24, 16), 256, 0, stream>>>(xb, w1, (void*)qkv, 2048, 3072, 1024, 1);
  rope_kernel<<<8192, 256, 0, stream>>>(qkv, cosT, sinT);
  transv_kernel<<<dim3(16, 32), 256, 0, stream>>>(qkv, vt);
  attn_split_kernel<<<dim3(144, 16), 256, 0, stream>>>(qkv, vt, pOh, pML);
  combine_kernel<<<dim3(32, 16), 256, 0, stream>>>(pOh, pML, lq1, lk1, lq2, lk2, gamma, atn);
  gemm_bt<<<dim3(8, 16), 256, 0, stream>>>(atn, wob, d_out, 2048, 1024, 1024, 0);
}